// Round 3
// baseline (542.326 us; speedup 1.0000x reference)
//
#include <hip/hip_runtime.h>
#include <stdint.h>
#include <stddef.h>

#define OBS 128
#define F1D 256
#define HD  128
#define NA  18
#define TT  128
#define BB  1024
#define NN  (TT*BB)

typedef __attribute__((ext_vector_type(8))) short short8;
typedef __attribute__((ext_vector_type(4))) float f32x4;

// ---- workspace layout (bytes) ----
#define WS_W1   0u          // [2][256*128] bf16
#define WS_W2   131072u     // [2][128*256] bf16
#define WS_WC   262144u     // [2][512*256] bf16 ([Wih|Whh], PRESCALED by -log2e / -2log2e)
#define WS_FLAG 786432u     // int action-dtype flag
#define WS_BIAS 787456u     // [2][512] f32 prescaled gate biases
#define WS_FEAT 791552u     // [2][NN*HD] bf16 feat, overwritten in-place by hs

#define LOG2E 1.442695041f

__device__ __forceinline__ unsigned short f2bf(float f) {
  union { float f; uint32_t u; } v; v.f = f;
  uint32_t u = v.u;
  u += 0x7fffu + ((u >> 16) & 1u);   // RNE
  return (unsigned short)(u >> 16);
}
__device__ __forceinline__ float bf2f(uint32_t hu) {
  union { uint32_t u; float f; } v; v.u = hu << 16;
  return v.f;
}
__device__ __forceinline__ f32x4 mfma16(short8 a, short8 b, f32x4 c) {
  return __builtin_amdgcn_mfma_f32_16x16x32_bf16(a, b, c, 0, 0, 0);
}
// asm load: output regs are opaque to the register allocator -> CANNOT be
// rematerialized; forces true VGPR residency of weight fragments (R2's
// VGPR_Count=108 proved the compiler re-streamed 128KB/step from L2).
__device__ __forceinline__ short8 ldg128(const unsigned short* p) {
  int4 r;
  asm volatile("global_load_dwordx4 %0, %1, off" : "=v"(r) : "v"(p));
  return *(short8*)&r;
}
// barrier with LDS-only drain: keeps feat prefetch + hs stores (vmcnt) in
// flight across the step boundary (compiler's __syncthreads drains vmcnt(0)).
__device__ __forceinline__ void wg_barrier() {
  asm volatile("s_waitcnt lgkmcnt(0)\n\ts_barrier" ::: "memory");
}

// ---------------- kernel 0: param prep ----------------
__global__ __launch_bounds__(256) void prep_kernel(
    const float* __restrict__ aw1, const float* __restrict__ cw1,
    const float* __restrict__ aw2, const float* __restrict__ cw2,
    const float* __restrict__ awih, const float* __restrict__ awhh,
    const float* __restrict__ cwih, const float* __restrict__ cwhh,
    const float* __restrict__ a_b, const float* __restrict__ c_b,
    const int* __restrict__ action,
    unsigned short* __restrict__ w1o, unsigned short* __restrict__ w2o,
    unsigned short* __restrict__ wco, float* __restrict__ sbias,
    int* __restrict__ flag)
{
  int bid = blockIdx.x;
  if (bid == (int)gridDim.x - 1) {
    __shared__ int any;
    if (threadIdx.x == 0) any = 0;
    __syncthreads();
    int local = 0;
    for (int i = threadIdx.x; i < 4096; i += 256)
      if ((i & 1) && action[i] != 0) local = 1;
    if (local) any = 1;
    __syncthreads();
    if (threadIdx.x == 0) flag[0] = any;
    // prescaled biases: [2][512]
    for (int j = threadIdx.x; j < 1024; j += 256) {
      int br = j >> 9, idx = j & 511;
      const float* src = br ? c_b : a_b;
      float sc = ((idx >> 7) == 2) ? -2.0f*LOG2E : -LOG2E;
      sbias[j] = src[idx] * sc;
    }
    return;
  }
  int i = bid * 256 + threadIdx.x;
  if (i < 65536) {
    int br = i >> 15, j = i & 32767;
    const float* s = br ? cw1 : aw1;
    w1o[i] = f2bf(s[j]);
  } else if (i < 131072) {
    int k = i - 65536;
    int br = k >> 15, j = k & 32767;
    const float* s = br ? cw2 : aw2;
    w2o[k] = f2bf(s[j]);
  } else {
    int k = i - 131072;
    int br = k >> 17, j = k & 131071;
    int n = j >> 8, kk = j & 255;
    const float* wih = br ? cwih : awih;
    const float* whh = br ? cwhh : awhh;
    float v = (kk < 128) ? wih[n*128 + kk] : whh[n*128 + (kk - 128)];
    float sc = ((n >> 7) == 2) ? -2.0f*LOG2E : -LOG2E;   // gate order i,f,g,o
    wco[k] = f2bf(v * sc);
  }
}

// ---------------- kernel 1: feature MLP (throughput mode) ----------------
// One 32-row tile per WG, 256 thr (4 waves), 8192 WGs -> deep oversubscription
// hides barriers/latency. B-frags loaded per ct/nt tile (short-lived, low VGPR).
__global__ __launch_bounds__(256) void feat_kernel(
    const float* __restrict__ x,
    const unsigned short* __restrict__ w1g, const unsigned short* __restrict__ w2g,
    const float* __restrict__ ab1, const float* __restrict__ cb1,
    const float* __restrict__ ab2, const float* __restrict__ cb2,
    const float* __restrict__ alnw, const float* __restrict__ clnw,
    const float* __restrict__ alnb, const float* __restrict__ clnb,
    unsigned short* __restrict__ featg)
{
  int br = blockIdx.y;
  const unsigned short* w1 = w1g + (size_t)br * (F1D*OBS);
  const unsigned short* w2 = w2g + (size_t)br * (HD*F1D);
  const float* b1 = br ? cb1 : ab1;
  const float* b2 = br ? cb2 : ab2;
  const float* lw = br ? clnw : alnw;
  const float* lb = br ? clnb : alnb;
  unsigned short* feat = featg + (size_t)br * NN * HD;
  int row0 = blockIdx.x * 32;

  __shared__ unsigned short xs[32*128];
  __shared__ unsigned short h1s[32*256];
  __shared__ float fs[32*132];
  __shared__ float lws[HD], lbs[HD];

  int tid = threadIdx.x;
  int w = tid >> 6, lane = tid & 63, q = lane >> 4, ln = lane & 15;

  // stage x tile (32x128 f32 -> bf16, chunk-XOR swizzled)
  const float* xp = x + (size_t)row0 * OBS;
  #pragma unroll
  for (int s = 0; s < 4; ++s) {
    int e4 = tid + s*256;
    int e  = e4 * 4;
    int r  = e >> 7, k = e & 127;
    float4 v = ((const float4*)xp)[e4];
    int sw = ((k >> 3) ^ (r & 15)) << 3;
    int ad = r*128 + sw + (k & 7);
    *(uint32_t*)&xs[ad]     = (uint32_t)f2bf(v.x) | ((uint32_t)f2bf(v.y) << 16);
    *(uint32_t*)&xs[ad + 2] = (uint32_t)f2bf(v.z) | ((uint32_t)f2bf(v.w) << 16);
  }
  if (tid < HD) { lws[tid] = lw[tid]; lbs[tid] = lb[tid]; }
  __syncthreads();

  // ---- G1: h1 = relu(x @ w1^T + b1) : wave w owns cols [w*64, w*64+64) ----
  short8 af[2][4];
  #pragma unroll
  for (int mt = 0; mt < 2; ++mt)
    #pragma unroll
    for (int kf = 0; kf < 4; ++kf)
      af[mt][kf] = *(const short8*)&xs[(mt*16 + ln)*128 + ((((kf<<2)|q) ^ ln) << 3)];
  #pragma unroll
  for (int ct = 0; ct < 4; ++ct) {
    int nn = w*64 + ct*16 + ln;
    float bv = b1[nn];
    short8 bf[4];
    #pragma unroll
    for (int kf = 0; kf < 4; ++kf)
      bf[kf] = *(const short8*)&w1[nn*OBS + kf*32 + q*8];
    #pragma unroll
    for (int mt = 0; mt < 2; ++mt) {
      f32x4 acc = {bv, bv, bv, bv};
      #pragma unroll
      for (int kf = 0; kf < 4; ++kf) acc = mfma16(af[mt][kf], bf[kf], acc);
      #pragma unroll
      for (int rg = 0; rg < 4; ++rg) {
        float v = acc[rg] > 0.0f ? acc[rg] : 0.0f;
        int rrow = mt*16 + q*4 + rg;
        int sw = ((nn >> 3) ^ (rrow & 15)) << 3;
        h1s[rrow*256 + sw + (nn & 7)] = f2bf(v);
      }
    }
  }
  __syncthreads();

  // ---- G2: f = h1 @ w2^T + b2 : wave w owns cols [w*32, w*32+32) ----
  short8 ah[2][8];
  #pragma unroll
  for (int mt = 0; mt < 2; ++mt)
    #pragma unroll
    for (int kf = 0; kf < 8; ++kf)
      ah[mt][kf] = *(const short8*)&h1s[(mt*16 + ln)*256 + ((((kf<<2)|q) ^ ln) << 3)];
  #pragma unroll
  for (int nt = 0; nt < 2; ++nt) {
    int nn = w*32 + nt*16 + ln;
    float bv = b2[nn];
    short8 bf[8];
    #pragma unroll
    for (int kf = 0; kf < 8; ++kf)
      bf[kf] = *(const short8*)&w2[nn*F1D + kf*32 + q*8];
    #pragma unroll
    for (int mt = 0; mt < 2; ++mt) {
      f32x4 acc = {bv, bv, bv, bv};
      #pragma unroll
      for (int kf = 0; kf < 8; ++kf) acc = mfma16(ah[mt][kf], bf[kf], acc);
      #pragma unroll
      for (int rg = 0; rg < 4; ++rg)
        fs[(mt*16 + q*4 + rg)*132 + nn] = acc[rg];
    }
  }
  __syncthreads();

  // ---- LN + relu + bf16 store: 32 rows x 8 threads/row ----
  {
    int r = tid >> 3, g = tid & 7;
    float v[16];
    float s = 0.0f, ss = 0.0f;
    #pragma unroll
    for (int j4 = 0; j4 < 4; ++j4) {
      float4 vv = *(const float4*)&fs[r*132 + g*16 + j4*4];
      v[j4*4+0] = vv.x; v[j4*4+1] = vv.y; v[j4*4+2] = vv.z; v[j4*4+3] = vv.w;
      s += vv.x + vv.y + vv.z + vv.w;
      ss += vv.x*vv.x + vv.y*vv.y + vv.z*vv.z + vv.w*vv.w;
    }
    #pragma unroll
    for (int m = 1; m < 8; m <<= 1) { s += __shfl_xor(s, m); ss += __shfl_xor(ss, m); }
    float mu = s * (1.0f/128.0f);
    float var = ss * (1.0f/128.0f) - mu*mu;
    float rstd = rsqrtf(var + 1e-5f);
    unsigned short ob[16];
    #pragma unroll
    for (int j = 0; j < 16; ++j) {
      int k = g*16 + j;
      float t = (v[j] - mu) * rstd * lws[k] + lbs[k];
      ob[j] = f2bf(t > 0.0f ? t : 0.0f);
    }
    unsigned short* dst = &feat[(size_t)(row0 + r)*HD + g*16];
    *(short8*)dst       = *(short8*)&ob[0];
    *(short8*)(dst + 8) = *(short8*)&ob[8];
  }
}

// ---------------- kernel 2: masked LSTM ----------------
// 128 WGs (2 branches x 64 chunks of 16 rows), 512 thr. Weight B-frags pinned
// via asm loads (128 VGPRs, no remat). One raw barrier/step (lgkmcnt-only
// drain): feat[t+1] register prefetch and hs stores stay in flight.
__global__ __launch_bounds__(512, 2) void lstm_kernel(
    const unsigned short* __restrict__ wcg,
    const float* __restrict__ sbias,
    const float* __restrict__ ah0, const float* __restrict__ ac0,
    const float* __restrict__ ch0, const float* __restrict__ cc0,
    const int* __restrict__ done,
    unsigned short* __restrict__ featg,
    float* __restrict__ dout)
{
  int bid = blockIdx.x;
  int br = bid >> 6;
  int base = (bid & 63) * 16;
  const unsigned short* wc = wcg + (size_t)br * (512*256);
  const float* sb = sbias + br*512;
  const float* h0 = br ? ch0 : ah0;
  const float* c0 = br ? cc0 : ac0;
  unsigned short* hsbuf = featg + (size_t)br * NN * HD;
  float* outh = dout + (size_t)(4 + br*2) * NN;
  float* outc = dout + (size_t)(5 + br*2) * NN;

  int tid = threadIdx.x;
  int w = tid >> 6, lane = tid & 63, q = lane >> 4, ln = lane & 15;
  int n = w*16 + ln;

  // pinned B-frags (prescaled weights)
  short8 bfr[4][8];
  float bias[4];
  #pragma unroll
  for (int g4 = 0; g4 < 4; ++g4) {
    int gn = g4*128 + n;
    bias[g4] = sb[gn];
    #pragma unroll
    for (int kf = 0; kf < 8; ++kf)
      bfr[g4][kf] = ldg128(&wc[gn*256 + kf*32 + q*8]);
  }
  asm volatile("s_waitcnt vmcnt(0)" ::: "memory");

  __shared__ float mls[TT*16];            // 1 - done
  __shared__ unsigned short hlds[2][16*128];
  for (int i = tid; i < TT*16; i += 512)
    mls[i] = 1.0f - (float)done[(i >> 4)*BB + base + (i & 15)];

  float hp[4], cp[4], h0v[4];
  #pragma unroll
  for (int rg = 0; rg < 4; ++rg) {
    int r = q*4 + rg;
    h0v[rg] = h0[(base + r)*HD + n];
    cp[rg]  = c0[(base + r)*HD + n];
    hp[rg]  = h0v[rg];
  }
  // prefetch feat[0]
  const unsigned short* fp = hsbuf + ((size_t)(base + ln))*HD;
  short8 afr[4];
  #pragma unroll
  for (int kf = 0; kf < 4; ++kf)
    afr[kf] = *(const short8*)&fp[kf*32 + q*8];
  unsigned short* sp = hsbuf + (size_t)(base + q*4)*HD + n;  // hs store base
  __syncthreads();  // mls ready
  {
    float4 m0 = *(const float4*)&mls[q*4];
    #pragma unroll
    for (int rg = 0; rg < 4; ++rg) {
      float m = (&m0.x)[rg];
      cp[rg] *= m;
      int r = q*4 + rg;
      hlds[0][r*128 + (((n >> 3) ^ r) << 3) + (n & 7)] = f2bf(h0v[rg] * m);
    }
  }
  __syncthreads();  // hlds[0] ready

  for (int t = 0; t < TT; ++t) {
    const unsigned short* hb = hlds[t & 1];
    unsigned short* hbn = hlds[(t & 1) ^ 1];
    short8 hfr[4];
    #pragma unroll
    for (int kf = 0; kf < 4; ++kf)
      hfr[kf] = *(const short8*)&hb[ln*128 + ((((kf<<2)|q) ^ ln) << 3)];
    // prefetch feat[t+1] (stays in flight across the raw barrier)
    fp += (size_t)BB * HD;
    short8 nfr[4];
    if (t < TT-1) {
      #pragma unroll
      for (int kf = 0; kf < 4; ++kf)
        nfr[kf] = *(const short8*)&fp[kf*32 + q*8];
    }
    f32x4 a0 = {bias[0],bias[0],bias[0],bias[0]};
    f32x4 a1 = {bias[1],bias[1],bias[1],bias[1]};
    f32x4 a2 = {bias[2],bias[2],bias[2],bias[2]};
    f32x4 a3 = {bias[3],bias[3],bias[3],bias[3]};
    #pragma unroll
    for (int kf = 0; kf < 4; ++kf) {
      a0 = mfma16(afr[kf], bfr[0][kf], a0);
      a1 = mfma16(afr[kf], bfr[1][kf], a1);
      a2 = mfma16(afr[kf], bfr[2][kf], a2);
      a3 = mfma16(afr[kf], bfr[3][kf], a3);
    }
    #pragma unroll
    for (int kf = 0; kf < 4; ++kf) {
      a0 = mfma16(hfr[kf], bfr[0][4+kf], a0);
      a1 = mfma16(hfr[kf], bfr[1][4+kf], a1);
      a2 = mfma16(hfr[kf], bfr[2][4+kf], a2);
      a3 = mfma16(hfr[kf], bfr[3][4+kf], a3);
    }
    float4 mn;
    if (t < TT-1) mn = *(const float4*)&mls[(t+1)*16 + q*4];
    else          mn = make_float4(1.0f, 1.0f, 1.0f, 1.0f);
    #pragma unroll
    for (int rg = 0; rg < 4; ++rg) {
      // weights/bias prescaled: sigm(x)=rcp(1+exp2(y)), tanh=2*rcp(1+exp2(y))-1
      float si = __builtin_amdgcn_rcpf(1.0f + __builtin_amdgcn_exp2f(a0[rg]));
      float sf = __builtin_amdgcn_rcpf(1.0f + __builtin_amdgcn_exp2f(a1[rg]));
      float tg = __builtin_fmaf(2.0f,
                   __builtin_amdgcn_rcpf(1.0f + __builtin_amdgcn_exp2f(a2[rg])), -1.0f);
      float so = __builtin_amdgcn_rcpf(1.0f + __builtin_amdgcn_exp2f(a3[rg]));
      float cn = __builtin_fmaf(sf, cp[rg], si*tg);
      float th = __builtin_fmaf(2.0f,
                   __builtin_amdgcn_rcpf(1.0f + __builtin_amdgcn_exp2f(-2.0f*LOG2E*cn)), -1.0f);
      float hn = so * th;
      unsigned short hu = f2bf(hn);
      sp[rg*HD] = hu;                          // hs[t] over feat[t], offset rg*256B
      bool live = ((&mn.x)[rg] != 0.0f);
      cp[rg] = live ? cn : 0.0f;
      hp[rg] = hn;
      int r = q*4 + rg;
      hbn[r*128 + (((n >> 3) ^ r) << 3) + (n & 7)] = live ? hu : (unsigned short)0;
    }
    sp += (size_t)BB * HD;
    wg_barrier();   // LDS-only drain
    #pragma unroll
    for (int kf = 0; kf < 4; ++kf) afr[kf] = nfr[kf];
  }
  #pragma unroll
  for (int rg = 0; rg < 4; ++rg) {
    int r = base + q*4 + rg;
    outh[r*HD + n] = hp[rg];
    outc[r*HD + n] = cp[rg];
  }
}

// ---------------- kernel 3: heads ----------------
__global__ __launch_bounds__(256) void head_kernel(
    const unsigned short* __restrict__ hsa, const unsigned short* __restrict__ hsc,
    const float* __restrict__ alnw, const float* __restrict__ alnb,
    const float* __restrict__ ahw, const float* __restrict__ ahb,
    const float* __restrict__ clnw, const float* __restrict__ clnb,
    const float* __restrict__ chw, const float* __restrict__ chb,
    const int* __restrict__ action, const int* __restrict__ flag,
    float* __restrict__ dout)
{
  __shared__ float whs[NA*HD];
  __shared__ float hbs[NA];
  __shared__ float alws[HD], albs[HD], clws[HD], clbs[HD], cws[HD];
  __shared__ float cbs;
  int tid = threadIdx.x;
  for (int i = tid; i < NA*HD; i += 256) whs[i] = ahw[i];
  if (tid < NA) hbs[tid] = ahb[tid];
  if (tid < HD) { alws[tid]=alnw[tid]; albs[tid]=alnb[tid];
                  clws[tid]=clnw[tid]; clbs[tid]=clnb[tid]; cws[tid]=chw[tid]; }
  if (tid == 0) cbs = chb[0];
  __syncthreads();

  int rr = blockIdx.x*256 + tid;
  int fl = flag[0];
  int act = fl ? action[rr] : (int)(((const long long*)action)[rr]);
  dout[rr] = (float)act;
  if (act < 0) act = 0;
  if (act > NA-1) act = NA-1;

  uint32_t hw_[64];
  // ---- actor ----
  {
    const uint32_t* hp = (const uint32_t*)(hsa + (size_t)rr*HD);
    for (int i = 0; i < 16; ++i) *(uint4*)&hw_[i*4] = ((const uint4*)hp)[i];
    float s = 0.0f, ss = 0.0f;
    for (int i = 0; i < 64; ++i) {
      float f0 = bf2f(hw_[i] & 0xffffu), f1 = bf2f(hw_[i] >> 16);
      s += f0 + f1; ss += f0*f0 + f1*f1;
    }
    float mu = s * (1.0f/128.0f);
    float var = ss * (1.0f/128.0f) - mu*mu;
    float rstd = rsqrtf(var + 1e-5f);
    float lg[NA];
    for (int a = 0; a < NA; ++a) lg[a] = hbs[a];
    for (int i = 0; i < 64; ++i) {
      int k0 = i*2;
      float f0 = (bf2f(hw_[i] & 0xffffu) - mu)*rstd*alws[k0]   + albs[k0];
      float f1 = (bf2f(hw_[i] >> 16)     - mu)*rstd*alws[k0+1] + albs[k0+1];
      for (int a = 0; a < NA; ++a)
        lg[a] += f0*whs[a*HD + k0] + f1*whs[a*HD + k0 + 1];
    }
    float mx = lg[0];
    for (int a = 1; a < NA; ++a) mx = fmaxf(mx, lg[a]);
    float se = 0.0f;
    for (int a = 0; a < NA; ++a) se += __expf(lg[a] - mx);
    float lse = __logf(se);
    dout[(size_t)NN + rr] = lg[act] - mx - lse;
    float ent = 0.0f;
    for (int a = 0; a < NA; ++a) { float lp = lg[a] - mx - lse; ent -= __expf(lp)*lp; }
    dout[(size_t)2*NN + rr] = ent;
  }
  // ---- critic ----
  {
    const uint32_t* hp = (const uint32_t*)(hsc + (size_t)rr*HD);
    for (int i = 0; i < 16; ++i) *(uint4*)&hw_[i*4] = ((const uint4*)hp)[i];
    float s = 0.0f, ss = 0.0f;
    for (int i = 0; i < 64; ++i) {
      float f0 = bf2f(hw_[i] & 0xffffu), f1 = bf2f(hw_[i] >> 16);
      s += f0 + f1; ss += f0*f0 + f1*f1;
    }
    float mu = s * (1.0f/128.0f);
    float var = ss * (1.0f/128.0f) - mu*mu;
    float rstd = rsqrtf(var + 1e-5f);
    float v = cbs;
    for (int i = 0; i < 64; ++i) {
      int k0 = i*2;
      float f0 = (bf2f(hw_[i] & 0xffffu) - mu)*rstd*clws[k0]   + clbs[k0];
      float f1 = (bf2f(hw_[i] >> 16)     - mu)*rstd*clws[k0+1] + clbs[k0+1];
      v += f0*cws[k0] + f1*cws[k0+1];
    }
    dout[(size_t)3*NN + rr] = v;
  }
}

extern "C" void kernel_launch(void* const* d_in, const int* in_sizes, int n_in,
                              void* d_out, int out_size, void* d_ws, size_t ws_size,
                              hipStream_t stream) {
  (void)in_sizes; (void)n_in; (void)out_size; (void)ws_size;
  const float* x    = (const float*)d_in[0];
  const float* ah0  = (const float*)d_in[1];
  const float* ac0  = (const float*)d_in[2];
  const float* ch0  = (const float*)d_in[3];
  const float* cc0  = (const float*)d_in[4];
  const int*   done = (const int*)d_in[5];
  const int*   act  = (const int*)d_in[6];
  const float* aw1  = (const float*)d_in[7];
  const float* ab1  = (const float*)d_in[8];
  const float* aw2  = (const float*)d_in[9];
  const float* ab2  = (const float*)d_in[10];
  const float* aflnw= (const float*)d_in[11];
  const float* aflnb= (const float*)d_in[12];
  const float* awih = (const float*)d_in[13];
  const float* awhh = (const float*)d_in[14];
  const float* a_b  = (const float*)d_in[15];
  const float* alnw = (const float*)d_in[16];
  const float* alnb = (const float*)d_in[17];
  const float* ahw  = (const float*)d_in[18];
  const float* ahb  = (const float*)d_in[19];
  const float* cw1  = (const float*)d_in[20];
  const float* cb1  = (const float*)d_in[21];
  const float* cw2  = (const float*)d_in[22];
  const float* cb2  = (const float*)d_in[23];
  const float* cflnw= (const float*)d_in[24];
  const float* cflnb= (const float*)d_in[25];
  const float* cwih = (const float*)d_in[26];
  const float* cwhh = (const float*)d_in[27];
  const float* c_b  = (const float*)d_in[28];
  const float* clnw = (const float*)d_in[29];
  const float* clnb = (const float*)d_in[30];
  const float* chw  = (const float*)d_in[31];
  const float* chb  = (const float*)d_in[32];

  char* ws = (char*)d_ws;
  unsigned short* w1b  = (unsigned short*)(ws + WS_W1);
  unsigned short* w2b  = (unsigned short*)(ws + WS_W2);
  unsigned short* wcb  = (unsigned short*)(ws + WS_WC);
  int*            flag = (int*)(ws + WS_FLAG);
  float*          sb   = (float*)(ws + WS_BIAS);
  unsigned short* featb= (unsigned short*)(ws + WS_FEAT);
  unsigned short* hsa  = featb;
  unsigned short* hsc  = featb + (size_t)NN * HD;
  float* out = (float*)d_out;

  prep_kernel<<<1537, 256, 0, stream>>>(aw1, cw1, aw2, cw2, awih, awhh, cwih, cwhh,
                                        a_b, c_b, act, w1b, w2b, wcb, sb, flag);
  feat_kernel<<<dim3(NN/32, 2), 256, 0, stream>>>(x, w1b, w2b, ab1, cb1, ab2, cb2,
                                                  aflnw, cflnw, aflnb, cflnb, featb);
  lstm_kernel<<<128, 512, 0, stream>>>(wcb, sb, ah0, ac0, ch0, cc0, done,
                                       featb, out);
  head_kernel<<<512, 256, 0, stream>>>(hsa, hsc, alnw, alnb, ahw, ahb,
                                       clnw, clnb, chw, chb, act, flag, out);
}

// Round 4
// 541.984 us; speedup vs baseline: 1.0006x; 1.0006x over previous
//
#include <hip/hip_runtime.h>
#include <stdint.h>
#include <stddef.h>

#define OBS 128
#define F1D 256
#define HD  128
#define NA  18
#define TT  128
#define BB  1024
#define NN  (TT*BB)

typedef __attribute__((ext_vector_type(8))) short short8;
typedef __attribute__((ext_vector_type(4))) float f32x4;

// ---- workspace layout (bytes) ----
#define WS_W1   0u          // [2][256*128] bf16
#define WS_W2   131072u     // [2][128*256] bf16
#define WS_WC   262144u     // [2][512*256] bf16 ([Wih|Whh], PRESCALED by -log2e / -2log2e)
#define WS_FLAG 786432u     // int action-dtype flag
#define WS_BIAS 787456u     // [2][512] f32 prescaled gate biases
#define WS_FEAT 791552u     // [2][NN*HD] bf16 feat, overwritten in-place by hs

#define LOG2E 1.442695041f

__device__ __forceinline__ unsigned short f2bf(float f) {
  union { float f; uint32_t u; } v; v.f = f;
  uint32_t u = v.u;
  u += 0x7fffu + ((u >> 16) & 1u);   // RNE
  return (unsigned short)(u >> 16);
}
__device__ __forceinline__ float bf2f(uint32_t hu) {
  union { uint32_t u; float f; } v; v.u = hu << 16;
  return v.f;
}
__device__ __forceinline__ f32x4 mfma16(short8 a, short8 b, f32x4 c) {
  return __builtin_amdgcn_mfma_f32_16x16x32_bf16(a, b, c, 0, 0, 0);
}
// asm load: outputs are opaque to the allocator -> cannot be rematerialized.
// Forces true residency of weight fragments (compiler may park them in AGPRs,
// which MFMA reads directly on gfx950's unified file -> free).
__device__ __forceinline__ short8 ldg128(const unsigned short* p) {
  int4 r;
  asm volatile("global_load_dwordx4 %0, %1, off" : "=v"(r) : "v"(p));
  return *(short8*)&r;
}

// ---------------- kernel 0: param prep ----------------
__global__ __launch_bounds__(256) void prep_kernel(
    const float* __restrict__ aw1, const float* __restrict__ cw1,
    const float* __restrict__ aw2, const float* __restrict__ cw2,
    const float* __restrict__ awih, const float* __restrict__ awhh,
    const float* __restrict__ cwih, const float* __restrict__ cwhh,
    const float* __restrict__ a_b, const float* __restrict__ c_b,
    const int* __restrict__ action,
    unsigned short* __restrict__ w1o, unsigned short* __restrict__ w2o,
    unsigned short* __restrict__ wco, float* __restrict__ sbias,
    int* __restrict__ flag)
{
  int bid = blockIdx.x;
  if (bid == (int)gridDim.x - 1) {
    __shared__ int any;
    if (threadIdx.x == 0) any = 0;
    __syncthreads();
    int local = 0;
    for (int i = threadIdx.x; i < 4096; i += 256)
      if ((i & 1) && action[i] != 0) local = 1;
    if (local) any = 1;
    __syncthreads();
    if (threadIdx.x == 0) flag[0] = any;
    for (int j = threadIdx.x; j < 1024; j += 256) {
      int br = j >> 9, idx = j & 511;
      const float* src = br ? c_b : a_b;
      float sc = ((idx >> 7) == 2) ? -2.0f*LOG2E : -LOG2E;
      sbias[j] = src[idx] * sc;
    }
    return;
  }
  int i = bid * 256 + threadIdx.x;
  if (i < 65536) {
    int br = i >> 15, j = i & 32767;
    const float* s = br ? cw1 : aw1;
    w1o[i] = f2bf(s[j]);
  } else if (i < 131072) {
    int k = i - 65536;
    int br = k >> 15, j = k & 32767;
    const float* s = br ? cw2 : aw2;
    w2o[k] = f2bf(s[j]);
  } else {
    int k = i - 131072;
    int br = k >> 17, j = k & 131071;
    int n = j >> 8, kk = j & 255;
    const float* wih = br ? cwih : awih;
    const float* whh = br ? cwhh : awhh;
    float v = (kk < 128) ? wih[n*128 + kk] : whh[n*128 + (kk - 128)];
    float sc = ((n >> 7) == 2) ? -2.0f*LOG2E : -LOG2E;   // gate order i,f,g,o
    wco[k] = f2bf(v * sc);
  }
}

// ---------------- kernel 1: feature MLP (persistent, register-pinned weights) ----------------
// 512 WGs (256 per branch), 256 thr (4 waves), 16 tiles of 32 rows each.
// Each wave owns disjoint output cols: G1 cols [w*64,w*64+64), G2 cols [w*32,+32).
// Its weight B-fragments (16+16 short8 = 128 regs) are asm-pinned ONCE ->
// weight traffic drops from ~3.1 GB (16384 short-lived WGs) to 32 MB.
// LDS: xs 8K + h1s 16K + lnsum 1K = 25 KB. LN via shfl + cross-wave partials.
__global__ __launch_bounds__(256, 1) void feat_kernel(
    const float* __restrict__ x,
    const unsigned short* __restrict__ w1g, const unsigned short* __restrict__ w2g,
    const float* __restrict__ ab1, const float* __restrict__ cb1,
    const float* __restrict__ ab2, const float* __restrict__ cb2,
    const float* __restrict__ alnw, const float* __restrict__ clnw,
    const float* __restrict__ alnb, const float* __restrict__ clnb,
    unsigned short* __restrict__ featg)
{
  int br = blockIdx.y;
  const unsigned short* w1 = w1g + (size_t)br * (F1D*OBS); // [256][128]
  const unsigned short* w2 = w2g + (size_t)br * (HD*F1D);  // [128][256]
  const float* b1 = br ? cb1 : ab1;
  const float* b2 = br ? cb2 : ab2;
  const float* lw = br ? clnw : alnw;
  const float* lb = br ? clnb : alnb;
  unsigned short* feat = featg + (size_t)br * NN * HD;

  __shared__ unsigned short xs[32*OBS];     // 8 KB, chunk-XOR swizzled
  __shared__ unsigned short h1s[32*F1D];    // 16 KB, swizzled
  __shared__ float lnsum[32*8];             // [row][wave*2 + {s,ss}]

  int tid = threadIdx.x;
  int w = tid >> 6, lane = tid & 63, q = lane >> 4, ln = lane & 15;

  // pinned weight fragments (disjoint per wave)
  short8 b1f[4][4]; float b1v[4];
  #pragma unroll
  for (int ct = 0; ct < 4; ++ct) {
    int nn = w*64 + ct*16 + ln;
    b1v[ct] = b1[nn];
    #pragma unroll
    for (int kf = 0; kf < 4; ++kf)
      b1f[ct][kf] = ldg128(&w1[nn*OBS + kf*32 + q*8]);
  }
  short8 b2f[2][8]; float b2v[2], lwv[2], lbv[2];
  #pragma unroll
  for (int nt = 0; nt < 2; ++nt) {
    int nn = w*32 + nt*16 + ln;
    b2v[nt] = b2[nn]; lwv[nt] = lw[nn]; lbv[nt] = lb[nn];
    #pragma unroll
    for (int kf = 0; kf < 8; ++kf)
      b2f[nt][kf] = ldg128(&w2[nn*F1D + kf*32 + q*8]);
  }
  asm volatile("s_waitcnt vmcnt(0)" ::: "memory");

  // first tile's x into regs
  float4 xr[4];
  {
    const float* xp = x + (size_t)(blockIdx.x*16)*32 * OBS;
    #pragma unroll
    for (int s = 0; s < 4; ++s) xr[s] = ((const float4*)xp)[tid + s*256];
  }

  for (int j = 0; j < 16; ++j) {
    int row0 = (blockIdx.x*16 + j) * 32;
    // write staged x regs -> xs (bf16, swizzled)
    #pragma unroll
    for (int s = 0; s < 4; ++s) {
      int e = (tid + s*256) * 4;
      int r = e >> 7, k = e & 127;
      int ad = r*128 + ((((k >> 3) ^ (r & 15)) << 3)) + (k & 7);
      uint2 d;
      d.x = (uint32_t)f2bf(xr[s].x) | ((uint32_t)f2bf(xr[s].y) << 16);
      d.y = (uint32_t)f2bf(xr[s].z) | ((uint32_t)f2bf(xr[s].w) << 16);
      *(uint2*)&xs[ad] = d;
    }
    __syncthreads();   // B1: xs ready
    // prefetch next tile's x (clamped reload on last iter)
    {
      int jn = (j < 15) ? j + 1 : 15;
      const float* xp = x + (size_t)(blockIdx.x*16 + jn)*32 * OBS;
      #pragma unroll
      for (int s = 0; s < 4; ++s) xr[s] = ((const float4*)xp)[tid + s*256];
    }
    // ---- G1: h1 = relu(x @ w1^T + b1) ----
    short8 af[2][4];
    #pragma unroll
    for (int mt = 0; mt < 2; ++mt)
      #pragma unroll
      for (int kf = 0; kf < 4; ++kf)
        af[mt][kf] = *(const short8*)&xs[(mt*16 + ln)*128 + ((((kf<<2)|q) ^ ln) << 3)];
    #pragma unroll
    for (int ct = 0; ct < 4; ++ct) {
      int nn = w*64 + ct*16 + ln;
      #pragma unroll
      for (int mt = 0; mt < 2; ++mt) {
        f32x4 acc = {b1v[ct], b1v[ct], b1v[ct], b1v[ct]};
        #pragma unroll
        for (int kf = 0; kf < 4; ++kf) acc = mfma16(af[mt][kf], b1f[ct][kf], acc);
        #pragma unroll
        for (int rg = 0; rg < 4; ++rg) {
          float v = acc[rg] > 0.0f ? acc[rg] : 0.0f;
          int rrow = mt*16 + q*4 + rg;
          h1s[rrow*256 + (((nn >> 3) ^ (rrow & 15)) << 3) + (nn & 7)] = f2bf(v);
        }
      }
    }
    __syncthreads();   // B2: h1s ready
    // ---- G2: f = h1 @ w2^T + b2 ----
    short8 ah[2][8];
    #pragma unroll
    for (int mt = 0; mt < 2; ++mt)
      #pragma unroll
      for (int kf = 0; kf < 8; ++kf)
        ah[mt][kf] = *(const short8*)&h1s[(mt*16 + ln)*256 + ((((kf<<2)|q) ^ ln) << 3)];
    f32x4 acc2[2][2];
    #pragma unroll
    for (int nt = 0; nt < 2; ++nt)
      #pragma unroll
      for (int mt = 0; mt < 2; ++mt) {
        f32x4 acc = {b2v[nt], b2v[nt], b2v[nt], b2v[nt]};
        #pragma unroll
        for (int kf = 0; kf < 8; ++kf) acc = mfma16(ah[mt][kf], b2f[nt][kf], acc);
        acc2[nt][mt] = acc;
      }
    // ---- LN partial sums (this wave's 32 cols), reduce over 16-lane groups ----
    #pragma unroll
    for (int mt = 0; mt < 2; ++mt)
      #pragma unroll
      for (int rg = 0; rg < 4; ++rg) {
        float v0 = acc2[0][mt][rg], v1 = acc2[1][mt][rg];
        float s = v0 + v1, ss = v0*v0 + v1*v1;
        #pragma unroll
        for (int m = 1; m < 16; m <<= 1) { s += __shfl_xor(s, m); ss += __shfl_xor(ss, m); }
        if (ln == 0) {
          int r = mt*16 + q*4 + rg;
          lnsum[r*8 + w*2]     = s;
          lnsum[r*8 + w*2 + 1] = ss;
        }
      }
    __syncthreads();   // B3: lnsum ready
    // ---- finish LN + relu + store ----
    #pragma unroll
    for (int mt = 0; mt < 2; ++mt)
      #pragma unroll
      for (int rg = 0; rg < 4; ++rg) {
        int r = mt*16 + q*4 + rg;
        float4 p0 = *(const float4*)&lnsum[r*8];
        float4 p1 = *(const float4*)&lnsum[r*8 + 4];
        float S  = p0.x + p0.z + p1.x + p1.z;
        float SS = p0.y + p0.w + p1.y + p1.w;
        float mu = S * (1.0f/128.0f);
        float var = SS * (1.0f/128.0f) - mu*mu;
        float rstd = rsqrtf(var + 1e-5f);
        #pragma unroll
        for (int nt = 0; nt < 2; ++nt) {
          float t = (acc2[nt][mt][rg] - mu) * rstd * lwv[nt] + lbv[nt];
          if (t < 0.0f) t = 0.0f;
          feat[(size_t)(row0 + r)*HD + w*32 + nt*16 + ln] = f2bf(t);
        }
      }
    __syncthreads();   // protect lnsum/h1s before next tile overwrites
  }
}

// ---------------- kernel 2: masked LSTM ----------------
// 128 WGs (2 branches x 64 chunks of 16 rows), 512 thr. Weight B-frags pinned
// via asm loads. __syncthreads per step (drain is ~free per R2/R3 A-B, and it
// makes the cross-step feat-prefetch vs hs-store ordering safe). Unroll-2
// removes register copies; offsets hoisted so loads/stores are saddr+imm.
__global__ __launch_bounds__(512, 2) void lstm_kernel(
    const unsigned short* __restrict__ wcg,
    const float* __restrict__ sbias,
    const float* __restrict__ ah0, const float* __restrict__ ac0,
    const float* __restrict__ ch0, const float* __restrict__ cc0,
    const int* __restrict__ done,
    unsigned short* __restrict__ featg,
    float* __restrict__ dout)
{
  int bid = blockIdx.x;
  int br = bid >> 6;
  int base = (bid & 63) * 16;
  const unsigned short* wc = wcg + (size_t)br * (512*256);
  const float* sb = sbias + br*512;
  const float* h0 = br ? ch0 : ah0;
  const float* c0 = br ? cc0 : ac0;
  unsigned short* hsbuf = featg + (size_t)br * NN * HD;
  float* outh = dout + (size_t)(4 + br*2) * NN;
  float* outc = dout + (size_t)(5 + br*2) * NN;

  int tid = threadIdx.x;
  int w = tid >> 6, lane = tid & 63, q = lane >> 4, ln = lane & 15;
  int n = w*16 + ln;

  short8 bfr[4][8];
  float bias[4];
  #pragma unroll
  for (int g4 = 0; g4 < 4; ++g4) {
    int gn = g4*128 + n;
    bias[g4] = sb[gn];
    #pragma unroll
    for (int kf = 0; kf < 8; ++kf)
      bfr[g4][kf] = ldg128(&wc[gn*256 + kf*32 + q*8]);
  }
  asm volatile("s_waitcnt vmcnt(0)" ::: "memory");

  __shared__ float mls[(TT+1)*16];          // 1 - done, padded with 1.0 at t=TT
  __shared__ unsigned short hlds[2][16*128];
  for (int i = tid; i < (TT+1)*16; i += 512)
    mls[i] = (i < TT*16) ? 1.0f - (float)done[(i >> 4)*BB + base + (i & 15)] : 1.0f;

  const int loff = (base + ln)*HD + q*8;    // feat load lane offset (elements)
  const int soff = (base + q*4)*HD + n;     // hs store lane offset
  int haddr[4], hoff[4];
  #pragma unroll
  for (int kf = 0; kf < 4; ++kf)
    haddr[kf] = ln*128 + ((((kf<<2)|q) ^ ln) << 3);
  #pragma unroll
  for (int rg = 0; rg < 4; ++rg) {
    int r = q*4 + rg;
    hoff[rg] = r*128 + (((n >> 3) ^ r) << 3) + (n & 7);
  }

  float hp[4], cp[4], h0v[4];
  #pragma unroll
  for (int rg = 0; rg < 4; ++rg) {
    int r = q*4 + rg;
    h0v[rg] = h0[(base + r)*HD + n];
    cp[rg]  = c0[(base + r)*HD + n];
    hp[rg]  = h0v[rg];
  }
  short8 afr[4], nfr[4];
  #pragma unroll
  for (int kf = 0; kf < 4; ++kf)            // feat[0]
    afr[kf] = *(const short8*)&hsbuf[loff + kf*32];
  __syncthreads();  // mls ready
  {
    float4 m0 = *(const float4*)&mls[q*4];
    #pragma unroll
    for (int rg = 0; rg < 4; ++rg) {
      float m = (&m0.x)[rg];
      cp[rg] *= m;
      hlds[0][hoff[rg]] = f2bf(h0v[rg] * m);
    }
  }
  __syncthreads();  // hlds[0] ready

#define LSTM_STEP(TTT, CUR, NXT, HB)                                           \
  {                                                                            \
    short8 hfr[4];                                                             \
    _Pragma("unroll")                                                          \
    for (int kf = 0; kf < 4; ++kf)                                             \
      hfr[kf] = *(const short8*)&hlds[HB][haddr[kf]];                          \
    int tn = ((TTT) + 1 < TT) ? (TTT) + 1 : TT - 1;                            \
    const unsigned short* fq = hsbuf + (size_t)tn * (BB*HD);                   \
    _Pragma("unroll")                                                          \
    for (int kf = 0; kf < 4; ++kf)                                             \
      NXT[kf] = *(const short8*)&fq[loff + kf*32];                             \
    f32x4 a0 = {bias[0],bias[0],bias[0],bias[0]};                              \
    f32x4 a1 = {bias[1],bias[1],bias[1],bias[1]};                              \
    f32x4 a2 = {bias[2],bias[2],bias[2],bias[2]};                              \
    f32x4 a3 = {bias[3],bias[3],bias[3],bias[3]};                              \
    _Pragma("unroll")                                                          \
    for (int kf = 0; kf < 4; ++kf) {                                           \
      a0 = mfma16(CUR[kf], bfr[0][kf], a0);                                    \
      a1 = mfma16(CUR[kf], bfr[1][kf], a1);                                    \
      a2 = mfma16(CUR[kf], bfr[2][kf], a2);                                    \
      a3 = mfma16(CUR[kf], bfr[3][kf], a3);                                    \
    }                                                                          \
    _Pragma("unroll")                                                          \
    for (int kf = 0; kf < 4; ++kf) {                                           \
      a0 = mfma16(hfr[kf], bfr[0][4+kf], a0);                                  \
      a1 = mfma16(hfr[kf], bfr[1][4+kf], a1);                                  \
      a2 = mfma16(hfr[kf], bfr[2][4+kf], a2);                                  \
      a3 = mfma16(hfr[kf], bfr[3][4+kf], a3);                                  \
    }                                                                          \
    float4 mn = *(const float4*)&mls[((TTT)+1)*16 + q*4];                      \
    unsigned short* sq = hsbuf + (size_t)(TTT) * (BB*HD);                      \
    _Pragma("unroll")                                                          \
    for (int rg = 0; rg < 4; ++rg) {                                           \
      float si = __builtin_amdgcn_rcpf(1.0f + __builtin_amdgcn_exp2f(a0[rg])); \
      float sf = __builtin_amdgcn_rcpf(1.0f + __builtin_amdgcn_exp2f(a1[rg])); \
      float tg = __builtin_fmaf(2.0f,                                          \
                   __builtin_amdgcn_rcpf(1.0f + __builtin_amdgcn_exp2f(a2[rg])), -1.0f); \
      float so = __builtin_amdgcn_rcpf(1.0f + __builtin_amdgcn_exp2f(a3[rg])); \
      float cn = __builtin_fmaf(sf, cp[rg], si*tg);                            \
      float th = __builtin_fmaf(2.0f,                                          \
                   __builtin_amdgcn_rcpf(1.0f + __builtin_amdgcn_exp2f(-2.0f*LOG2E*cn)), -1.0f); \
      float hn = so * th;                                                      \
      unsigned short hu = f2bf(hn);                                            \
      sq[soff + rg*HD] = hu;                                                   \
      bool live = ((&mn.x)[rg] != 0.0f);                                       \
      cp[rg] = live ? cn : 0.0f;                                               \
      hp[rg] = hn;                                                             \
      hlds[(HB)^1][hoff[rg]] = live ? hu : (unsigned short)0;                  \
    }                                                                          \
    __syncthreads();                                                           \
  }

  for (int t = 0; t < TT; t += 2) {
    LSTM_STEP(t,   afr, nfr, 0)
    LSTM_STEP(t+1, nfr, afr, 1)
  }
#undef LSTM_STEP

  #pragma unroll
  for (int rg = 0; rg < 4; ++rg) {
    int r = base + q*4 + rg;
    outh[r*HD + n] = hp[rg];
    outc[r*HD + n] = cp[rg];
  }
}

// ---------------- kernel 3: heads ----------------
__global__ __launch_bounds__(256) void head_kernel(
    const unsigned short* __restrict__ hsa, const unsigned short* __restrict__ hsc,
    const float* __restrict__ alnw, const float* __restrict__ alnb,
    const float* __restrict__ ahw, const float* __restrict__ ahb,
    const float* __restrict__ clnw, const float* __restrict__ clnb,
    const float* __restrict__ chw, const float* __restrict__ chb,
    const int* __restrict__ action, const int* __restrict__ flag,
    float* __restrict__ dout)
{
  __shared__ float whs[NA*HD];
  __shared__ float hbs[NA];
  __shared__ float alws[HD], albs[HD], clws[HD], clbs[HD], cws[HD];
  __shared__ float cbs;
  int tid = threadIdx.x;
  for (int i = tid; i < NA*HD; i += 256) whs[i] = ahw[i];
  if (tid < NA) hbs[tid] = ahb[tid];
  if (tid < HD) { alws[tid]=alnw[tid]; albs[tid]=alnb[tid];
                  clws[tid]=clnw[tid]; clbs[tid]=clnb[tid]; cws[tid]=chw[tid]; }
  if (tid == 0) cbs = chb[0];
  __syncthreads();

  int rr = blockIdx.x*256 + tid;
  int fl = flag[0];
  int act = fl ? action[rr] : (int)(((const long long*)action)[rr]);
  dout[rr] = (float)act;
  if (act < 0) act = 0;
  if (act > NA-1) act = NA-1;

  uint32_t hw_[64];
  // ---- actor ----
  {
    const uint32_t* hp = (const uint32_t*)(hsa + (size_t)rr*HD);
    for (int i = 0; i < 16; ++i) *(uint4*)&hw_[i*4] = ((const uint4*)hp)[i];
    float s = 0.0f, ss = 0.0f;
    for (int i = 0; i < 64; ++i) {
      float f0 = bf2f(hw_[i] & 0xffffu), f1 = bf2f(hw_[i] >> 16);
      s += f0 + f1; ss += f0*f0 + f1*f1;
    }
    float mu = s * (1.0f/128.0f);
    float var = ss * (1.0f/128.0f) - mu*mu;
    float rstd = rsqrtf(var + 1e-5f);
    float lg[NA];
    for (int a = 0; a < NA; ++a) lg[a] = hbs[a];
    for (int i = 0; i < 64; ++i) {
      int k0 = i*2;
      float f0 = (bf2f(hw_[i] & 0xffffu) - mu)*rstd*alws[k0]   + albs[k0];
      float f1 = (bf2f(hw_[i] >> 16)     - mu)*rstd*alws[k0+1] + albs[k0+1];
      for (int a = 0; a < NA; ++a)
        lg[a] += f0*whs[a*HD + k0] + f1*whs[a*HD + k0 + 1];
    }
    float mx = lg[0];
    for (int a = 1; a < NA; ++a) mx = fmaxf(mx, lg[a]);
    float se = 0.0f;
    for (int a = 0; a < NA; ++a) se += __expf(lg[a] - mx);
    float lse = __logf(se);
    dout[(size_t)NN + rr] = lg[act] - mx - lse;
    float ent = 0.0f;
    for (int a = 0; a < NA; ++a) { float lp = lg[a] - mx - lse; ent -= __expf(lp)*lp; }
    dout[(size_t)2*NN + rr] = ent;
  }
  // ---- critic ----
  {
    const uint32_t* hp = (const uint32_t*)(hsc + (size_t)rr*HD);
    for (int i = 0; i < 16; ++i) *(uint4*)&hw_[i*4] = ((const uint4*)hp)[i];
    float s = 0.0f, ss = 0.0f;
    for (int i = 0; i < 64; ++i) {
      float f0 = bf2f(hw_[i] & 0xffffu), f1 = bf2f(hw_[i] >> 16);
      s += f0 + f1; ss += f0*f0 + f1*f1;
    }
    float mu = s * (1.0f/128.0f);
    float var = ss * (1.0f/128.0f) - mu*mu;
    float rstd = rsqrtf(var + 1e-5f);
    float v = cbs;
    for (int i = 0; i < 64; ++i) {
      int k0 = i*2;
      float f0 = (bf2f(hw_[i] & 0xffffu) - mu)*rstd*clws[k0]   + clbs[k0];
      float f1 = (bf2f(hw_[i] >> 16)     - mu)*rstd*clws[k0+1] + clbs[k0+1];
      v += f0*cws[k0] + f1*cws[k0+1];
    }
    dout[(size_t)3*NN + rr] = v;
  }
}

extern "C" void kernel_launch(void* const* d_in, const int* in_sizes, int n_in,
                              void* d_out, int out_size, void* d_ws, size_t ws_size,
                              hipStream_t stream) {
  (void)in_sizes; (void)n_in; (void)out_size; (void)ws_size;
  const float* x    = (const float*)d_in[0];
  const float* ah0  = (const float*)d_in[1];
  const float* ac0  = (const float*)d_in[2];
  const float* ch0  = (const float*)d_in[3];
  const float* cc0  = (const float*)d_in[4];
  const int*   done = (const int*)d_in[5];
  const int*   act  = (const int*)d_in[6];
  const float* aw1  = (const float*)d_in[7];
  const float* ab1  = (const float*)d_in[8];
  const float* aw2  = (const float*)d_in[9];
  const float* ab2  = (const float*)d_in[10];
  const float* aflnw= (const float*)d_in[11];
  const float* aflnb= (const float*)d_in[12];
  const float* awih = (const float*)d_in[13];
  const float* awhh = (const float*)d_in[14];
  const float* a_b  = (const float*)d_in[15];
  const float* alnw = (const float*)d_in[16];
  const float* alnb = (const float*)d_in[17];
  const float* ahw  = (const float*)d_in[18];
  const float* ahb  = (const float*)d_in[19];
  const float* cw1  = (const float*)d_in[20];
  const float* cb1  = (const float*)d_in[21];
  const float* cw2  = (const float*)d_in[22];
  const float* cb2  = (const float*)d_in[23];
  const float* cflnw= (const float*)d_in[24];
  const float* cflnb= (const float*)d_in[25];
  const float* cwih = (const float*)d_in[26];
  const float* cwhh = (const float*)d_in[27];
  const float* c_b  = (const float*)d_in[28];
  const float* clnw = (const float*)d_in[29];
  const float* clnb = (const float*)d_in[30];
  const float* chw  = (const float*)d_in[31];
  const float* chb  = (const float*)d_in[32];

  char* ws = (char*)d_ws;
  unsigned short* w1b  = (unsigned short*)(ws + WS_W1);
  unsigned short* w2b  = (unsigned short*)(ws + WS_W2);
  unsigned short* wcb  = (unsigned short*)(ws + WS_WC);
  int*            flag = (int*)(ws + WS_FLAG);
  float*          sb   = (float*)(ws + WS_BIAS);
  unsigned short* featb= (unsigned short*)(ws + WS_FEAT);
  unsigned short* hsa  = featb;
  unsigned short* hsc  = featb + (size_t)NN * HD;
  float* out = (float*)d_out;

  prep_kernel<<<1537, 256, 0, stream>>>(aw1, cw1, aw2, cw2, awih, awhh, cwih, cwhh,
                                        a_b, c_b, act, w1b, w2b, wcb, sb, flag);
  feat_kernel<<<dim3(256, 2), 256, 0, stream>>>(x, w1b, w2b, ab1, cb1, ab2, cb2,
                                                aflnw, cflnw, aflnb, cflnb, featb);
  lstm_kernel<<<128, 512, 0, stream>>>(wcb, sb, ah0, ac0, ch0, cc0, done,
                                       featb, out);
  head_kernel<<<512, 256, 0, stream>>>(hsa, hsc, alnw, alnb, ahw, ahb,
                                       clnw, clnb, chw, chb, act, flag, out);
}

// Round 5
// 509.345 us; speedup vs baseline: 1.0648x; 1.0641x over previous
//
#include <hip/hip_runtime.h>
#include <stdint.h>
#include <stddef.h>

#define OBS 128
#define F1D 256
#define HD  128
#define NA  18
#define TT  128
#define BB  1024
#define NN  (TT*BB)

typedef __attribute__((ext_vector_type(8))) short short8;
typedef __attribute__((ext_vector_type(4))) float f32x4;

// ---- workspace layout (bytes) ----
#define WS_W1   0u          // [2][256*128] bf16
#define WS_W2   131072u     // [2][128*256] bf16
#define WS_WC   262144u     // [2][512*256] bf16 ([Wih|Whh], PRESCALED by -log2e / -2log2e)
#define WS_FLAG 786432u     // int action-dtype flag
#define WS_BIAS 787456u     // [2][512] f32 prescaled gate biases
#define WS_FEAT 791552u     // [2][NN*HD] bf16 feat, overwritten in-place by hs

#define LOG2E 1.442695041f

__device__ __forceinline__ unsigned short f2bf(float f) {
  union { float f; uint32_t u; } v; v.f = f;
  uint32_t u = v.u;
  u += 0x7fffu + ((u >> 16) & 1u);   // RNE
  return (unsigned short)(u >> 16);
}
__device__ __forceinline__ float bf2f(uint32_t hu) {
  union { uint32_t u; float f; } v; v.u = hu << 16;
  return v.f;
}
__device__ __forceinline__ f32x4 mfma16(short8 a, short8 b, f32x4 c) {
  return __builtin_amdgcn_mfma_f32_16x16x32_bf16(a, b, c, 0, 0, 0);
}
// asm load: outputs are opaque to the allocator -> cannot be rematerialized.
__device__ __forceinline__ short8 ldg128(const unsigned short* p) {
  int4 r;
  asm volatile("global_load_dwordx4 %0, %1, off" : "=v"(r) : "v"(p));
  return *(short8*)&r;
}

// ---------------- kernel 0: param prep ----------------
__global__ __launch_bounds__(256) void prep_kernel(
    const float* __restrict__ aw1, const float* __restrict__ cw1,
    const float* __restrict__ aw2, const float* __restrict__ cw2,
    const float* __restrict__ awih, const float* __restrict__ awhh,
    const float* __restrict__ cwih, const float* __restrict__ cwhh,
    const float* __restrict__ a_b, const float* __restrict__ c_b,
    const int* __restrict__ action,
    unsigned short* __restrict__ w1o, unsigned short* __restrict__ w2o,
    unsigned short* __restrict__ wco, float* __restrict__ sbias,
    int* __restrict__ flag)
{
  int bid = blockIdx.x;
  if (bid == (int)gridDim.x - 1) {
    __shared__ int any;
    if (threadIdx.x == 0) any = 0;
    __syncthreads();
    int local = 0;
    for (int i = threadIdx.x; i < 4096; i += 256)
      if ((i & 1) && action[i] != 0) local = 1;
    if (local) any = 1;
    __syncthreads();
    if (threadIdx.x == 0) flag[0] = any;
    for (int j = threadIdx.x; j < 1024; j += 256) {
      int br = j >> 9, idx = j & 511;
      const float* src = br ? c_b : a_b;
      float sc = ((idx >> 7) == 2) ? -2.0f*LOG2E : -LOG2E;
      sbias[j] = src[idx] * sc;
    }
    return;
  }
  int i = bid * 256 + threadIdx.x;
  if (i < 65536) {
    int br = i >> 15, j = i & 32767;
    const float* s = br ? cw1 : aw1;
    w1o[i] = f2bf(s[j]);
  } else if (i < 131072) {
    int k = i - 65536;
    int br = k >> 15, j = k & 32767;
    const float* s = br ? cw2 : aw2;
    w2o[k] = f2bf(s[j]);
  } else {
    int k = i - 131072;
    int br = k >> 17, j = k & 131071;
    int n = j >> 8, kk = j & 255;
    const float* wih = br ? cwih : awih;
    const float* whh = br ? cwhh : awhh;
    float v = (kk < 128) ? wih[n*128 + kk] : whh[n*128 + (kk - 128)];
    float sc = ((n >> 7) == 2) ? -2.0f*LOG2E : -LOG2E;   // gate order i,f,g,o
    wco[k] = f2bf(v * sc);
  }
}

// ---------------- kernel 1: feature MLP (persistent, register-pinned weights) ----------------
__global__ __launch_bounds__(256, 1) void feat_kernel(
    const float* __restrict__ x,
    const unsigned short* __restrict__ w1g, const unsigned short* __restrict__ w2g,
    const float* __restrict__ ab1, const float* __restrict__ cb1,
    const float* __restrict__ ab2, const float* __restrict__ cb2,
    const float* __restrict__ alnw, const float* __restrict__ clnw,
    const float* __restrict__ alnb, const float* __restrict__ clnb,
    unsigned short* __restrict__ featg)
{
  int br = blockIdx.y;
  const unsigned short* w1 = w1g + (size_t)br * (F1D*OBS); // [256][128]
  const unsigned short* w2 = w2g + (size_t)br * (HD*F1D);  // [128][256]
  const float* b1 = br ? cb1 : ab1;
  const float* b2 = br ? cb2 : ab2;
  const float* lw = br ? clnw : alnw;
  const float* lb = br ? clnb : alnb;
  unsigned short* feat = featg + (size_t)br * NN * HD;

  __shared__ unsigned short xs[32*OBS];     // 8 KB, chunk-XOR swizzled
  __shared__ unsigned short h1s[32*F1D];    // 16 KB, swizzled
  __shared__ float lnsum[32*8];             // [row][wave*2 + {s,ss}]

  int tid = threadIdx.x;
  int w = tid >> 6, lane = tid & 63, q = lane >> 4, ln = lane & 15;

  // pinned weight fragments (disjoint per wave)
  short8 b1f[4][4]; float b1v[4];
  #pragma unroll
  for (int ct = 0; ct < 4; ++ct) {
    int nn = w*64 + ct*16 + ln;
    b1v[ct] = b1[nn];
    #pragma unroll
    for (int kf = 0; kf < 4; ++kf)
      b1f[ct][kf] = ldg128(&w1[nn*OBS + kf*32 + q*8]);
  }
  short8 b2f[2][8]; float b2v[2], lwv[2], lbv[2];
  #pragma unroll
  for (int nt = 0; nt < 2; ++nt) {
    int nn = w*32 + nt*16 + ln;
    b2v[nt] = b2[nn]; lwv[nt] = lw[nn]; lbv[nt] = lb[nn];
    #pragma unroll
    for (int kf = 0; kf < 8; ++kf)
      b2f[nt][kf] = ldg128(&w2[nn*F1D + kf*32 + q*8]);
  }
  asm volatile("s_waitcnt vmcnt(0)" ::: "memory");

  // first tile's x into regs
  float4 xr[4];
  {
    const float* xp = x + (size_t)(blockIdx.x*16)*32 * OBS;
    #pragma unroll
    for (int s = 0; s < 4; ++s) xr[s] = ((const float4*)xp)[tid + s*256];
  }

  for (int j = 0; j < 16; ++j) {
    int row0 = (blockIdx.x*16 + j) * 32;
    #pragma unroll
    for (int s = 0; s < 4; ++s) {
      int e = (tid + s*256) * 4;
      int r = e >> 7, k = e & 127;
      int ad = r*128 + ((((k >> 3) ^ (r & 15)) << 3)) + (k & 7);
      uint2 d;
      d.x = (uint32_t)f2bf(xr[s].x) | ((uint32_t)f2bf(xr[s].y) << 16);
      d.y = (uint32_t)f2bf(xr[s].z) | ((uint32_t)f2bf(xr[s].w) << 16);
      *(uint2*)&xs[ad] = d;
    }
    __syncthreads();   // B1: xs ready
    {
      int jn = (j < 15) ? j + 1 : 15;
      const float* xp = x + (size_t)(blockIdx.x*16 + jn)*32 * OBS;
      #pragma unroll
      for (int s = 0; s < 4; ++s) xr[s] = ((const float4*)xp)[tid + s*256];
    }
    // ---- G1 ----
    short8 af[2][4];
    #pragma unroll
    for (int mt = 0; mt < 2; ++mt)
      #pragma unroll
      for (int kf = 0; kf < 4; ++kf)
        af[mt][kf] = *(const short8*)&xs[(mt*16 + ln)*128 + ((((kf<<2)|q) ^ ln) << 3)];
    #pragma unroll
    for (int ct = 0; ct < 4; ++ct) {
      int nn = w*64 + ct*16 + ln;
      #pragma unroll
      for (int mt = 0; mt < 2; ++mt) {
        f32x4 acc = {b1v[ct], b1v[ct], b1v[ct], b1v[ct]};
        #pragma unroll
        for (int kf = 0; kf < 4; ++kf) acc = mfma16(af[mt][kf], b1f[ct][kf], acc);
        #pragma unroll
        for (int rg = 0; rg < 4; ++rg) {
          float v = acc[rg] > 0.0f ? acc[rg] : 0.0f;
          int rrow = mt*16 + q*4 + rg;
          h1s[rrow*256 + (((nn >> 3) ^ (rrow & 15)) << 3) + (nn & 7)] = f2bf(v);
        }
      }
    }
    __syncthreads();   // B2: h1s ready
    // ---- G2 ----
    short8 ah[2][8];
    #pragma unroll
    for (int mt = 0; mt < 2; ++mt)
      #pragma unroll
      for (int kf = 0; kf < 8; ++kf)
        ah[mt][kf] = *(const short8*)&h1s[(mt*16 + ln)*256 + ((((kf<<2)|q) ^ ln) << 3)];
    f32x4 acc2[2][2];
    #pragma unroll
    for (int nt = 0; nt < 2; ++nt)
      #pragma unroll
      for (int mt = 0; mt < 2; ++mt) {
        f32x4 acc = {b2v[nt], b2v[nt], b2v[nt], b2v[nt]};
        #pragma unroll
        for (int kf = 0; kf < 8; ++kf) acc = mfma16(ah[mt][kf], b2f[nt][kf], acc);
        acc2[nt][mt] = acc;
      }
    // ---- LN partials ----
    #pragma unroll
    for (int mt = 0; mt < 2; ++mt)
      #pragma unroll
      for (int rg = 0; rg < 4; ++rg) {
        float v0 = acc2[0][mt][rg], v1 = acc2[1][mt][rg];
        float s = v0 + v1, ss = v0*v0 + v1*v1;
        #pragma unroll
        for (int m = 1; m < 16; m <<= 1) { s += __shfl_xor(s, m); ss += __shfl_xor(ss, m); }
        if (ln == 0) {
          int r = mt*16 + q*4 + rg;
          lnsum[r*8 + w*2]     = s;
          lnsum[r*8 + w*2 + 1] = ss;
        }
      }
    __syncthreads();   // B3: lnsum ready
    #pragma unroll
    for (int mt = 0; mt < 2; ++mt)
      #pragma unroll
      for (int rg = 0; rg < 4; ++rg) {
        int r = mt*16 + q*4 + rg;
        float4 p0 = *(const float4*)&lnsum[r*8];
        float4 p1 = *(const float4*)&lnsum[r*8 + 4];
        float S  = p0.x + p0.z + p1.x + p1.z;
        float SS = p0.y + p0.w + p1.y + p1.w;
        float mu = S * (1.0f/128.0f);
        float var = SS * (1.0f/128.0f) - mu*mu;
        float rstd = rsqrtf(var + 1e-5f);
        #pragma unroll
        for (int nt = 0; nt < 2; ++nt) {
          float t = (acc2[nt][mt][rg] - mu) * rstd * lwv[nt] + lbv[nt];
          if (t < 0.0f) t = 0.0f;
          feat[(size_t)(row0 + r)*HD + w*32 + nt*16 + ln] = f2bf(t);
        }
      }
    __syncthreads();
  }
}

// ---------------- kernel 2: masked LSTM ----------------
// 128 WGs (2 branches x 64 chunks of 16 rows), 512 thr. Weight B-frags pinned.
// DELAYED hs store: step t's h values are held in regs and stored at the START
// of step t+1 -> the store latency is hidden behind the whole step instead of
// being drained by the barrier right after issue (R4: stores issued immediately
// before __syncthreads' vmcnt(0) -> ~300-500 cyc exposed drain per step).
// Step 0 issues a harmless dummy store to region 0 (overwritten by the real
// hs[0] store at step 1; vmcnt(0) barrier between them orders the two).
__global__ __launch_bounds__(512, 2) void lstm_kernel(
    const unsigned short* __restrict__ wcg,
    const float* __restrict__ sbias,
    const float* __restrict__ ah0, const float* __restrict__ ac0,
    const float* __restrict__ ch0, const float* __restrict__ cc0,
    const int* __restrict__ done,
    unsigned short* __restrict__ featg,
    float* __restrict__ dout)
{
  int bid = blockIdx.x;
  int br = bid >> 6;
  int base = (bid & 63) * 16;
  const unsigned short* wc = wcg + (size_t)br * (512*256);
  const float* sb = sbias + br*512;
  const float* h0 = br ? ch0 : ah0;
  const float* c0 = br ? cc0 : ac0;
  unsigned short* hsbuf = featg + (size_t)br * NN * HD;
  float* outh = dout + (size_t)(4 + br*2) * NN;
  float* outc = dout + (size_t)(5 + br*2) * NN;

  int tid = threadIdx.x;
  int w = tid >> 6, lane = tid & 63, q = lane >> 4, ln = lane & 15;
  int n = w*16 + ln;

  short8 bfr[4][8];
  float bias[4];
  #pragma unroll
  for (int g4 = 0; g4 < 4; ++g4) {
    int gn = g4*128 + n;
    bias[g4] = sb[gn];
    #pragma unroll
    for (int kf = 0; kf < 8; ++kf)
      bfr[g4][kf] = ldg128(&wc[gn*256 + kf*32 + q*8]);
  }
  asm volatile("s_waitcnt vmcnt(0)" ::: "memory");

  __shared__ float mls[(TT+1)*16];          // 1 - done, padded with 1.0 at t=TT
  __shared__ unsigned short hlds[2][16*128];
  for (int i = tid; i < (TT+1)*16; i += 512)
    mls[i] = (i < TT*16) ? 1.0f - (float)done[(i >> 4)*BB + base + (i & 15)] : 1.0f;

  const int loff = (base + ln)*HD + q*8;    // feat load lane offset (elements)
  const int soff = (base + q*4)*HD + n;     // hs store lane offset
  int haddr[4], hoff[4];
  #pragma unroll
  for (int kf = 0; kf < 4; ++kf)
    haddr[kf] = ln*128 + ((((kf<<2)|q) ^ ln) << 3);
  #pragma unroll
  for (int rg = 0; rg < 4; ++rg) {
    int r = q*4 + rg;
    hoff[rg] = r*128 + (((n >> 3) ^ r) << 3) + (n & 7);
  }

  float hp[4], cp[4], h0v[4];
  unsigned short hu_prev[4];
  #pragma unroll
  for (int rg = 0; rg < 4; ++rg) {
    int r = q*4 + rg;
    h0v[rg] = h0[(base + r)*HD + n];
    cp[rg]  = c0[(base + r)*HD + n];
    hp[rg]  = h0v[rg];
    hu_prev[rg] = 0;   // dummy for step-0 store (overwritten at step 1)
  }
  short8 afr[4], nfr[4];
  #pragma unroll
  for (int kf = 0; kf < 4; ++kf)            // feat[0]
    afr[kf] = *(const short8*)&hsbuf[loff + kf*32];
  __syncthreads();  // mls ready
  {
    float4 m0 = *(const float4*)&mls[q*4];
    #pragma unroll
    for (int rg = 0; rg < 4; ++rg) {
      float m = (&m0.x)[rg];
      cp[rg] *= m;
      hlds[0][hoff[rg]] = f2bf(h0v[rg] * m);
    }
  }
  __syncthreads();  // hlds[0] ready

#define LSTM_STEP(TTT, CUR, NXT, HB)                                           \
  {                                                                            \
    short8 hfr[4];                                                             \
    _Pragma("unroll")                                                          \
    for (int kf = 0; kf < 4; ++kf)                                             \
      hfr[kf] = *(const short8*)&hlds[HB][haddr[kf]];                          \
    /* delayed hs store for step TTT-1 (TTT==0: dummy to region 0, safe) */    \
    {                                                                          \
      int tp = (TTT) > 0 ? (TTT) - 1 : 0;                                      \
      unsigned short* sq = hsbuf + (size_t)tp * (BB*HD);                       \
      _Pragma("unroll")                                                        \
      for (int rg = 0; rg < 4; ++rg) sq[soff + rg*HD] = hu_prev[rg];           \
    }                                                                          \
    int tn = ((TTT) + 1 < TT) ? (TTT) + 1 : TT - 1;                            \
    const unsigned short* fq = hsbuf + (size_t)tn * (BB*HD);                   \
    _Pragma("unroll")                                                          \
    for (int kf = 0; kf < 4; ++kf)                                             \
      NXT[kf] = *(const short8*)&fq[loff + kf*32];                             \
    f32x4 a0 = {bias[0],bias[0],bias[0],bias[0]};                              \
    f32x4 a1 = {bias[1],bias[1],bias[1],bias[1]};                              \
    f32x4 a2 = {bias[2],bias[2],bias[2],bias[2]};                              \
    f32x4 a3 = {bias[3],bias[3],bias[3],bias[3]};                              \
    _Pragma("unroll")                                                          \
    for (int kf = 0; kf < 4; ++kf) {                                           \
      a0 = mfma16(CUR[kf], bfr[0][kf], a0);                                    \
      a1 = mfma16(CUR[kf], bfr[1][kf], a1);                                    \
      a2 = mfma16(CUR[kf], bfr[2][kf], a2);                                    \
      a3 = mfma16(CUR[kf], bfr[3][kf], a3);                                    \
    }                                                                          \
    _Pragma("unroll")                                                          \
    for (int kf = 0; kf < 4; ++kf) {                                           \
      a0 = mfma16(hfr[kf], bfr[0][4+kf], a0);                                  \
      a1 = mfma16(hfr[kf], bfr[1][4+kf], a1);                                  \
      a2 = mfma16(hfr[kf], bfr[2][4+kf], a2);                                  \
      a3 = mfma16(hfr[kf], bfr[3][4+kf], a3);                                  \
    }                                                                          \
    float4 mn = *(const float4*)&mls[((TTT)+1)*16 + q*4];                      \
    _Pragma("unroll")                                                          \
    for (int rg = 0; rg < 4; ++rg) {                                           \
      float si = __builtin_amdgcn_rcpf(1.0f + __builtin_amdgcn_exp2f(a0[rg])); \
      float sf = __builtin_amdgcn_rcpf(1.0f + __builtin_amdgcn_exp2f(a1[rg])); \
      float tg = __builtin_fmaf(2.0f,                                          \
                   __builtin_amdgcn_rcpf(1.0f + __builtin_amdgcn_exp2f(a2[rg])), -1.0f); \
      float so = __builtin_amdgcn_rcpf(1.0f + __builtin_amdgcn_exp2f(a3[rg])); \
      float cn = __builtin_fmaf(sf, cp[rg], si*tg);                            \
      float th = __builtin_fmaf(2.0f,                                          \
                   __builtin_amdgcn_rcpf(1.0f + __builtin_amdgcn_exp2f(-2.0f*LOG2E*cn)), -1.0f); \
      float hn = so * th;                                                      \
      unsigned short hu = f2bf(hn);                                            \
      hu_prev[rg] = hu;                                                        \
      bool live = ((&mn.x)[rg] != 0.0f);                                       \
      cp[rg] = live ? cn : 0.0f;                                               \
      hp[rg] = hn;                                                             \
      hlds[(HB)^1][hoff[rg]] = live ? hu : (unsigned short)0;                  \
    }                                                                          \
    __syncthreads();                                                           \
  }

  for (int t = 0; t < TT; t += 2) {
    LSTM_STEP(t,   afr, nfr, 0)
    LSTM_STEP(t+1, nfr, afr, 1)
  }
#undef LSTM_STEP

  // final hs[127] store + final states
  {
    unsigned short* sq = hsbuf + (size_t)(TT-1) * (BB*HD);
    #pragma unroll
    for (int rg = 0; rg < 4; ++rg) sq[soff + rg*HD] = hu_prev[rg];
  }
  #pragma unroll
  for (int rg = 0; rg < 4; ++rg) {
    int r = base + q*4 + rg;
    outh[r*HD + n] = hp[rg];
    outc[r*HD + n] = cp[rg];
  }
}

// ---------------- kernel 3: heads ----------------
__global__ __launch_bounds__(256) void head_kernel(
    const unsigned short* __restrict__ hsa, const unsigned short* __restrict__ hsc,
    const float* __restrict__ alnw, const float* __restrict__ alnb,
    const float* __restrict__ ahw, const float* __restrict__ ahb,
    const float* __restrict__ clnw, const float* __restrict__ clnb,
    const float* __restrict__ chw, const float* __restrict__ chb,
    const int* __restrict__ action, const int* __restrict__ flag,
    float* __restrict__ dout)
{
  __shared__ float whs[NA*HD];
  __shared__ float hbs[NA];
  __shared__ float alws[HD], albs[HD], clws[HD], clbs[HD], cws[HD];
  __shared__ float cbs;
  int tid = threadIdx.x;
  for (int i = tid; i < NA*HD; i += 256) whs[i] = ahw[i];
  if (tid < NA) hbs[tid] = ahb[tid];
  if (tid < HD) { alws[tid]=alnw[tid]; albs[tid]=alnb[tid];
                  clws[tid]=clnw[tid]; clbs[tid]=clnb[tid]; cws[tid]=chw[tid]; }
  if (tid == 0) cbs = chb[0];
  __syncthreads();

  int rr = blockIdx.x*256 + tid;
  int fl = flag[0];
  int act = fl ? action[rr] : (int)(((const long long*)action)[rr]);
  dout[rr] = (float)act;
  if (act < 0) act = 0;
  if (act > NA-1) act = NA-1;

  uint32_t hw_[64];
  // ---- actor ----
  {
    const uint32_t* hp = (const uint32_t*)(hsa + (size_t)rr*HD);
    for (int i = 0; i < 16; ++i) *(uint4*)&hw_[i*4] = ((const uint4*)hp)[i];
    float s = 0.0f, ss = 0.0f;
    for (int i = 0; i < 64; ++i) {
      float f0 = bf2f(hw_[i] & 0xffffu), f1 = bf2f(hw_[i] >> 16);
      s += f0 + f1; ss += f0*f0 + f1*f1;
    }
    float mu = s * (1.0f/128.0f);
    float var = ss * (1.0f/128.0f) - mu*mu;
    float rstd = rsqrtf(var + 1e-5f);
    float lg[NA];
    for (int a = 0; a < NA; ++a) lg[a] = hbs[a];
    for (int i = 0; i < 64; ++i) {
      int k0 = i*2;
      float f0 = (bf2f(hw_[i] & 0xffffu) - mu)*rstd*alws[k0]   + albs[k0];
      float f1 = (bf2f(hw_[i] >> 16)     - mu)*rstd*alws[k0+1] + albs[k0+1];
      for (int a = 0; a < NA; ++a)
        lg[a] += f0*whs[a*HD + k0] + f1*whs[a*HD + k0 + 1];
    }
    float mx = lg[0];
    for (int a = 1; a < NA; ++a) mx = fmaxf(mx, lg[a]);
    float se = 0.0f;
    for (int a = 0; a < NA; ++a) se += __expf(lg[a] - mx);
    float lse = __logf(se);
    dout[(size_t)NN + rr] = lg[act] - mx - lse;
    float ent = 0.0f;
    for (int a = 0; a < NA; ++a) { float lp = lg[a] - mx - lse; ent -= __expf(lp)*lp; }
    dout[(size_t)2*NN + rr] = ent;
  }
  // ---- critic ----
  {
    const uint32_t* hp = (const uint32_t*)(hsc + (size_t)rr*HD);
    for (int i = 0; i < 16; ++i) *(uint4*)&hw_[i*4] = ((const uint4*)hp)[i];
    float s = 0.0f, ss = 0.0f;
    for (int i = 0; i < 64; ++i) {
      float f0 = bf2f(hw_[i] & 0xffffu), f1 = bf2f(hw_[i] >> 16);
      s += f0 + f1; ss += f0*f0 + f1*f1;
    }
    float mu = s * (1.0f/128.0f);
    float var = ss * (1.0f/128.0f) - mu*mu;
    float rstd = rsqrtf(var + 1e-5f);
    float v = cbs;
    for (int i = 0; i < 64; ++i) {
      int k0 = i*2;
      float f0 = (bf2f(hw_[i] & 0xffffu) - mu)*rstd*clws[k0]   + clbs[k0];
      float f1 = (bf2f(hw_[i] >> 16)     - mu)*rstd*clws[k0+1] + clbs[k0+1];
      v += f0*cws[k0] + f1*cws[k0+1];
    }
    dout[(size_t)3*NN + rr] = v;
  }
}

extern "C" void kernel_launch(void* const* d_in, const int* in_sizes, int n_in,
                              void* d_out, int out_size, void* d_ws, size_t ws_size,
                              hipStream_t stream) {
  (void)in_sizes; (void)n_in; (void)out_size; (void)ws_size;
  const float* x    = (const float*)d_in[0];
  const float* ah0  = (const float*)d_in[1];
  const float* ac0  = (const float*)d_in[2];
  const float* ch0  = (const float*)d_in[3];
  const float* cc0  = (const float*)d_in[4];
  const int*   done = (const int*)d_in[5];
  const int*   act  = (const int*)d_in[6];
  const float* aw1  = (const float*)d_in[7];
  const float* ab1  = (const float*)d_in[8];
  const float* aw2  = (const float*)d_in[9];
  const float* ab2  = (const float*)d_in[10];
  const float* aflnw= (const float*)d_in[11];
  const float* aflnb= (const float*)d_in[12];
  const float* awih = (const float*)d_in[13];
  const float* awhh = (const float*)d_in[14];
  const float* a_b  = (const float*)d_in[15];
  const float* alnw = (const float*)d_in[16];
  const float* alnb = (const float*)d_in[17];
  const float* ahw  = (const float*)d_in[18];
  const float* ahb  = (const float*)d_in[19];
  const float* cw1  = (const float*)d_in[20];
  const float* cb1  = (const float*)d_in[21];
  const float* cw2  = (const float*)d_in[22];
  const float* cb2  = (const float*)d_in[23];
  const float* cflnw= (const float*)d_in[24];
  const float* cflnb= (const float*)d_in[25];
  const float* cwih = (const float*)d_in[26];
  const float* cwhh = (const float*)d_in[27];
  const float* c_b  = (const float*)d_in[28];
  const float* clnw = (const float*)d_in[29];
  const float* clnb = (const float*)d_in[30];
  const float* chw  = (const float*)d_in[31];
  const float* chb  = (const float*)d_in[32];

  char* ws = (char*)d_ws;
  unsigned short* w1b  = (unsigned short*)(ws + WS_W1);
  unsigned short* w2b  = (unsigned short*)(ws + WS_W2);
  unsigned short* wcb  = (unsigned short*)(ws + WS_WC);
  int*            flag = (int*)(ws + WS_FLAG);
  float*          sb   = (float*)(ws + WS_BIAS);
  unsigned short* featb= (unsigned short*)(ws + WS_FEAT);
  unsigned short* hsa  = featb;
  unsigned short* hsc  = featb + (size_t)NN * HD;
  float* out = (float*)d_out;

  prep_kernel<<<1537, 256, 0, stream>>>(aw1, cw1, aw2, cw2, awih, awhh, cwih, cwhh,
                                        a_b, c_b, act, w1b, w2b, wcb, sb, flag);
  feat_kernel<<<dim3(256, 2), 256, 0, stream>>>(x, w1b, w2b, ab1, cb1, ab2, cb2,
                                                aflnw, cflnw, aflnb, cflnb, featb);
  lstm_kernel<<<128, 512, 0, stream>>>(wcb, sb, ah0, ac0, ch0, cc0, done,
                                       featb, out);
  head_kernel<<<512, 256, 0, stream>>>(hsa, hsc, alnw, alnb, ahw, ahb,
                                       clnw, clnb, chw, chb, act, flag, out);
}

// Round 8
// 446.360 us; speedup vs baseline: 1.2150x; 1.1411x over previous
//
#include <hip/hip_runtime.h>
#include <stdint.h>
#include <stddef.h>

#define OBS 128
#define F1D 256
#define HD  128
#define NA  18
#define TT  128
#define BB  1024
#define NN  (TT*BB)
#define LOG2E 1.442695041f

typedef __attribute__((ext_vector_type(8))) short short8;
typedef __attribute__((ext_vector_type(4))) float f32x4;

__device__ __forceinline__ unsigned short f2bf(float f) {
  union { float f; uint32_t u; } v; v.f = f;
  uint32_t u = v.u;
  u += 0x7fffu + ((u >> 16) & 1u);   // RNE
  return (unsigned short)(u >> 16);
}
__device__ __forceinline__ float bf2f(uint32_t hu) {
  union { uint32_t u; float f; } v; v.u = hu << 16;
  return v.f;
}
__device__ __forceinline__ f32x4 mfma16(short8 a, short8 b, f32x4 c) {
  return __builtin_amdgcn_mfma_f32_16x16x32_bf16(a, b, c, 0, 0, 0);
}
// f32 -> bf16 fragment (8 consecutive, scaled)
__device__ __forceinline__ short8 cvt8(const float* p, float sc) {
  float4 a = *(const float4*)p;
  float4 b = *(const float4*)(p + 4);
  union { unsigned short u[8]; short8 s; } o;
  o.u[0]=f2bf(a.x*sc); o.u[1]=f2bf(a.y*sc); o.u[2]=f2bf(a.z*sc); o.u[3]=f2bf(a.w*sc);
  o.u[4]=f2bf(b.x*sc); o.u[5]=f2bf(b.y*sc); o.u[6]=f2bf(b.z*sc); o.u[7]=f2bf(b.w*sc);
  return o.s;
}
// pin: empty volatile asm with TIED SCALAR "+v" operands. Zero instructions,
// value becomes opaque -> no rematerialization. (R6: tied indirect int4 "+v"
// rejected by backend; R7: multi-inst asm w/o early-clobber let outputs alias
// inputs -> silent weight corruption. Scalar tied operands avoid both.)
__device__ __forceinline__ short8 pin(short8 v) {
  int4 i = *(int4*)&v;
  asm volatile("" : "+v"(i.x), "+v"(i.y), "+v"(i.z), "+v"(i.w));
  return *(short8*)&i;
}

// One WG = (branch, 8-batch-row slice). Fully self-contained:
// Phase A: feature MLP for its 1024 rows (t=0..127 x 8 batch cols)
// Phase B: masked LSTM on its 8 rows (stride-2 A-row packing: 2 cells/lane)
// Phase C: head (actor: logp/entropy; critic: value) on its own hs rows.
__global__ __launch_bounds__(512, 2) void fused_kernel(
    const float* __restrict__ x, const int* __restrict__ done,
    const int* __restrict__ action,
    const float* __restrict__ aw1, const float* __restrict__ ab1,
    const float* __restrict__ aw2, const float* __restrict__ ab2,
    const float* __restrict__ aflnw, const float* __restrict__ aflnb,
    const float* __restrict__ awih, const float* __restrict__ awhh,
    const float* __restrict__ a_b,
    const float* __restrict__ alnw, const float* __restrict__ alnb,
    const float* __restrict__ ahw, const float* __restrict__ ahb,
    const float* __restrict__ cw1, const float* __restrict__ cb1,
    const float* __restrict__ cw2, const float* __restrict__ cb2,
    const float* __restrict__ cflnw, const float* __restrict__ cflnb,
    const float* __restrict__ cwih, const float* __restrict__ cwhh,
    const float* __restrict__ c_b,
    const float* __restrict__ clnw, const float* __restrict__ clnb,
    const float* __restrict__ chw, const float* __restrict__ chb,
    const float* __restrict__ ah0, const float* __restrict__ ac0,
    const float* __restrict__ ch0, const float* __restrict__ cc0,
    unsigned short* __restrict__ featg, float* __restrict__ dout)
{
  int g = blockIdx.x;
  int br = g >> 7;
  int chunk = g & 127;
  int base8 = chunk * 8;

  const float* w1  = br ? cw1 : aw1;     // [256][128]
  const float* b1  = br ? cb1 : ab1;
  const float* w2  = br ? cw2 : aw2;     // [128][256]
  const float* b2  = br ? cb2 : ab2;
  const float* flw = br ? cflnw : aflnw;
  const float* flb = br ? cflnb : aflnb;
  const float* wih = br ? cwih : awih;   // [512][128]
  const float* whh = br ? cwhh : awhh;
  const float* gb  = br ? c_b : a_b;
  const float* h0  = br ? ch0 : ah0;
  const float* c0  = br ? cc0 : ac0;
  unsigned short* feat = featg + (size_t)br * NN * HD;

  __shared__ unsigned short xs[2][32*OBS];     // per-team swizzled x tile
  __shared__ unsigned short h1s[2][32*F1D];    // per-team swizzled h1 tile
  __shared__ float lnsum[2][32*8];
  __shared__ float mls[(TT+1)*8];              // 1 - done, padded t=TT
  __shared__ unsigned short hlds[2][8*128];    // double-buffered masked h
  __shared__ float hwl[NA*HD];                 // head weights (actor)
  __shared__ float pa[HD], pb[HD], pc[HD];
  __shared__ float hbl[NA];
  __shared__ int flagS;

  int tid = threadIdx.x;
  int w = tid >> 6, lane = tid & 63, q = lane >> 4, ln = lane & 15;
  int team = tid >> 8, t_tid = tid & 255, w4 = w & 3;

  // ================= Phase A: feature MLP =================
  {
    // pinned weights (converted f32->bf16 inline; no prep kernel)
    short8 b1f[4][4]; float b1v[4];
    #pragma unroll
    for (int ct = 0; ct < 4; ++ct) {
      int nn = w4*64 + ct*16 + ln;
      b1v[ct] = b1[nn];
      #pragma unroll
      for (int kf = 0; kf < 4; ++kf)
        b1f[ct][kf] = pin(cvt8(&w1[nn*OBS + kf*32 + q*8], 1.0f));
    }
    short8 b2f[2][8]; float b2v[2], lwv[2], lbv[2];
    #pragma unroll
    for (int nt = 0; nt < 2; ++nt) {
      int nn = w4*32 + nt*16 + ln;
      b2v[nt] = b2[nn]; lwv[nt] = flw[nn]; lbv[nt] = flb[nn];
      #pragma unroll
      for (int kf = 0; kf < 8; ++kf)
        b2f[nt][kf] = pin(cvt8(&w2[nn*F1D + kf*32 + q*8], 1.0f));
    }
    // tile = 4 timesteps x 8 batch rows = 32 rows; team handles tiles 2j+team
    float4 xr[4];
    #pragma unroll
    for (int s = 0; s < 4; ++s) {
      int e4 = t_tid + s*256;
      int r = e4 >> 5, c4 = e4 & 31;
      size_t grow = (size_t)(team*4 + (r>>3))*BB + base8 + (r&7);
      xr[s] = ((const float4*)x)[grow*32 + c4];
    }
    for (int j = 0; j < 16; ++j) {
      int jj = j*2 + team;
      #pragma unroll
      for (int s = 0; s < 4; ++s) {
        int e = (t_tid + s*256) * 4;
        int r = e >> 7, k = e & 127;
        int ad = r*128 + ((((k>>3) ^ (r&15)) << 3)) + (k&7);
        uint2 d;
        d.x = (uint32_t)f2bf(xr[s].x) | ((uint32_t)f2bf(xr[s].y) << 16);
        d.y = (uint32_t)f2bf(xr[s].z) | ((uint32_t)f2bf(xr[s].w) << 16);
        *(uint2*)&xs[team][ad] = d;
      }
      __syncthreads();                 // B1: xs ready
      {
        int jjn = (j < 15) ? jj + 2 : jj;
        #pragma unroll
        for (int s = 0; s < 4; ++s) {
          int e4 = t_tid + s*256;
          int r = e4 >> 5, c4 = e4 & 31;
          size_t grow = (size_t)(jjn*4 + (r>>3))*BB + base8 + (r&7);
          xr[s] = ((const float4*)x)[grow*32 + c4];
        }
      }
      // ---- G1: h1 = relu(x @ w1^T + b1) ----
      short8 af[2][4];
      #pragma unroll
      for (int mt = 0; mt < 2; ++mt)
        #pragma unroll
        for (int kf = 0; kf < 4; ++kf)
          af[mt][kf] = *(const short8*)&xs[team][(mt*16 + ln)*128 + ((((kf<<2)|q) ^ ln) << 3)];
      #pragma unroll
      for (int ct = 0; ct < 4; ++ct) {
        int nn = w4*64 + ct*16 + ln;
        #pragma unroll
        for (int mt = 0; mt < 2; ++mt) {
          f32x4 acc = {b1v[ct], b1v[ct], b1v[ct], b1v[ct]};
          #pragma unroll
          for (int kf = 0; kf < 4; ++kf) acc = mfma16(af[mt][kf], b1f[ct][kf], acc);
          #pragma unroll
          for (int rg = 0; rg < 4; ++rg) {
            float v = acc[rg] > 0.0f ? acc[rg] : 0.0f;
            int rrow = mt*16 + q*4 + rg;
            h1s[team][rrow*256 + (((nn>>3) ^ (rrow&15)) << 3) + (nn&7)] = f2bf(v);
          }
        }
      }
      __syncthreads();                 // B2: h1s ready
      // ---- G2: f = h1 @ w2^T + b2 (per-mt ah to cap VGPR) ----
      f32x4 acc2[2][2];
      #pragma unroll
      for (int mt = 0; mt < 2; ++mt) {
        short8 ah[8];
        #pragma unroll
        for (int kf = 0; kf < 8; ++kf)
          ah[kf] = *(const short8*)&h1s[team][(mt*16 + ln)*256 + ((((kf<<2)|q) ^ ln) << 3)];
        #pragma unroll
        for (int nt = 0; nt < 2; ++nt) {
          f32x4 acc = {b2v[nt], b2v[nt], b2v[nt], b2v[nt]};
          #pragma unroll
          for (int kf = 0; kf < 8; ++kf) acc = mfma16(ah[kf], b2f[nt][kf], acc);
          acc2[nt][mt] = acc;
        }
      }
      // ---- LN partials ----
      #pragma unroll
      for (int mt = 0; mt < 2; ++mt)
        #pragma unroll
        for (int rg = 0; rg < 4; ++rg) {
          float v0 = acc2[0][mt][rg], v1 = acc2[1][mt][rg];
          float s = v0 + v1, ssq = v0*v0 + v1*v1;
          #pragma unroll
          for (int m = 1; m < 16; m <<= 1) { s += __shfl_xor(s, m); ssq += __shfl_xor(ssq, m); }
          if (ln == 0) {
            int r = mt*16 + q*4 + rg;
            lnsum[team][r*8 + w4*2]     = s;
            lnsum[team][r*8 + w4*2 + 1] = ssq;
          }
        }
      __syncthreads();                 // B3: lnsum ready
      #pragma unroll
      for (int mt = 0; mt < 2; ++mt)
        #pragma unroll
        for (int rg = 0; rg < 4; ++rg) {
          int r = mt*16 + q*4 + rg;
          float4 p0 = *(const float4*)&lnsum[team][r*8];
          float4 p1 = *(const float4*)&lnsum[team][r*8 + 4];
          float S  = p0.x + p0.z + p1.x + p1.z;
          float SS = p0.y + p0.w + p1.y + p1.w;
          float mu = S * (1.0f/128.0f);
          float var = SS * (1.0f/128.0f) - mu*mu;
          float rstd = rsqrtf(var + 1e-5f);
          size_t grow = (size_t)(jj*4 + (r>>3))*BB + base8 + (r&7);
          #pragma unroll
          for (int nt = 0; nt < 2; ++nt) {
            float t = (acc2[nt][mt][rg] - mu) * rstd * lwv[nt] + lbv[nt];
            if (t < 0.0f) t = 0.0f;
            feat[grow*HD + w4*32 + nt*16 + ln] = f2bf(t);
          }
        }
      __syncthreads();                 // Bend
    }
  }

  // ================= Phase B: masked LSTM (M=8, stride-2 packing) =================
  int n = w*16 + ln;
  short8 bfr[4][8]; float bias[4];
  #pragma unroll
  for (int g4 = 0; g4 < 4; ++g4) {
    int gn = g4*128 + n;
    float sc = (g4 == 2) ? -2.0f*LOG2E : -LOG2E;   // gate order i,f,g,o
    bias[g4] = gb[gn] * sc;
    #pragma unroll
    for (int kf = 0; kf < 8; ++kf) {
      const float* src = (kf < 4) ? &wih[gn*HD + kf*32 + q*8]
                                  : &whh[gn*HD + (kf-4)*32 + q*8];
      bfr[g4][kf] = pin(cvt8(src, sc));
    }
  }
  for (int i = tid; i < (TT+1)*8; i += 512)
    mls[i] = (i < TT*8) ? 1.0f - (float)done[(i>>3)*BB + base8 + (i&7)] : 1.0f;

  const int loff = (base8 + (ln>>1))*HD + q*8;   // A-row ln -> batch row ln>>1
  int soff[2], hoffw[2], haddr[4];
  #pragma unroll
  for (int j = 0; j < 2; ++j) {
    int r = q*2 + j;                              // this lane's 2 batch rows
    soff[j]  = (base8 + r)*HD + n;
    hoffw[j] = r*128 + (((n>>3) ^ r) << 3) + (n&7);
  }
  #pragma unroll
  for (int kf = 0; kf < 4; ++kf) {
    int rr = ln >> 1;
    haddr[kf] = rr*128 + ((((kf<<2)|q) ^ rr) << 3);
  }
  float hp[2], cp[2]; unsigned short hu_prev[2];
  #pragma unroll
  for (int j = 0; j < 2; ++j) {
    int b = base8 + q*2 + j;
    hp[j] = h0[b*HD + n];
    cp[j] = c0[b*HD + n];
    hu_prev[j] = 0;                               // step-0 dummy store
  }
  short8 afr[4], nfr[4];
  #pragma unroll
  for (int kf = 0; kf < 4; ++kf)
    afr[kf] = *(const short8*)&feat[loff + kf*32];    // feat[0]
  __syncthreads();   // mls ready
  #pragma unroll
  for (int j = 0; j < 2; ++j) {
    float m = mls[q*2 + j];
    cp[j] *= m;
    hlds[0][hoffw[j]] = f2bf(hp[j] * m);
  }
  __syncthreads();   // hlds[0] ready

#define LSTM_STEP(TTT, CUR, NXT, HB)                                           \
  {                                                                            \
    short8 hfr[4];                                                             \
    _Pragma("unroll")                                                          \
    for (int kf = 0; kf < 4; ++kf)                                             \
      hfr[kf] = *(const short8*)&hlds[HB][haddr[kf]];                          \
    {                                                                          \
      int tp = (TTT) > 0 ? (TTT) - 1 : 0;                                      \
      unsigned short* sq = feat + (size_t)tp * (BB*HD);                        \
      sq[soff[0]] = hu_prev[0];                                                \
      sq[soff[1]] = hu_prev[1];                                                \
    }                                                                          \
    int tn = ((TTT) + 1 < TT) ? (TTT) + 1 : TT - 1;                            \
    const unsigned short* fq = feat + (size_t)tn * (BB*HD);                    \
    _Pragma("unroll")                                                          \
    for (int kf = 0; kf < 4; ++kf)                                             \
      NXT[kf] = *(const short8*)&fq[loff + kf*32];                             \
    f32x4 a0 = {bias[0],bias[0],bias[0],bias[0]};                              \
    f32x4 a1 = {bias[1],bias[1],bias[1],bias[1]};                              \
    f32x4 a2 = {bias[2],bias[2],bias[2],bias[2]};                              \
    f32x4 a3 = {bias[3],bias[3],bias[3],bias[3]};                              \
    _Pragma("unroll")                                                          \
    for (int kf = 0; kf < 4; ++kf) {                                           \
      a0 = mfma16(CUR[kf], bfr[0][kf], a0);                                    \
      a1 = mfma16(CUR[kf], bfr[1][kf], a1);                                    \
      a2 = mfma16(CUR[kf], bfr[2][kf], a2);                                    \
      a3 = mfma16(CUR[kf], bfr[3][kf], a3);                                    \
    }                                                                          \
    _Pragma("unroll")                                                          \
    for (int kf = 0; kf < 4; ++kf) {                                           \
      a0 = mfma16(hfr[kf], bfr[0][4+kf], a0);                                  \
      a1 = mfma16(hfr[kf], bfr[1][4+kf], a1);                                  \
      a2 = mfma16(hfr[kf], bfr[2][4+kf], a2);                                  \
      a3 = mfma16(hfr[kf], bfr[3][4+kf], a3);                                  \
    }                                                                          \
    float2 mn = *(const float2*)&mls[((TTT)+1)*8 + q*2];                       \
    _Pragma("unroll")                                                          \
    for (int j = 0; j < 2; ++j) {                                              \
      int rg = j*2;  /* C rows duplicated pairwise; even reg = valid copy */   \
      float si = __builtin_amdgcn_rcpf(1.0f + __builtin_amdgcn_exp2f(a0[rg])); \
      float sf = __builtin_amdgcn_rcpf(1.0f + __builtin_amdgcn_exp2f(a1[rg])); \
      float tg = __builtin_fmaf(2.0f,                                          \
                   __builtin_amdgcn_rcpf(1.0f + __builtin_amdgcn_exp2f(a2[rg])), -1.0f); \
      float so = __builtin_amdgcn_rcpf(1.0f + __builtin_amdgcn_exp2f(a3[rg])); \
      float cn = __builtin_fmaf(sf, cp[j], si*tg);                             \
      float th = __builtin_fmaf(2.0f,                                          \
                   __builtin_amdgcn_rcpf(1.0f + __builtin_amdgcn_exp2f(-2.0f*LOG2E*cn)), -1.0f); \
      float hn = so * th;                                                      \
      unsigned short hu = f2bf(hn);                                            \
      hu_prev[j] = hu;                                                         \
      bool live = ((&mn.x)[j] != 0.0f);                                        \
      cp[j] = live ? cn : 0.0f;                                                \
      hp[j] = hn;                                                              \
      hlds[(HB)^1][hoffw[j]] = live ? hu : (unsigned short)0;                  \
    }                                                                          \
    __syncthreads();                                                           \
  }

  for (int t = 0; t < TT; t += 2) {
    LSTM_STEP(t,   afr, nfr, 0)
    LSTM_STEP(t+1, nfr, afr, 1)
  }
#undef LSTM_STEP

  {
    unsigned short* sq = feat + (size_t)(TT-1)*(BB*HD);
    sq[soff[0]] = hu_prev[0];
    sq[soff[1]] = hu_prev[1];
  }
  {
    float* outh = dout + (size_t)(4 + br*2) * NN;
    float* outc = dout + (size_t)(5 + br*2) * NN;
    #pragma unroll
    for (int j = 0; j < 2; ++j) {
      int b = base8 + q*2 + j;
      outh[b*HD + n] = hp[j];
      outc[b*HD + n] = cp[j];
    }
  }

  // ================= Phase C: heads =================
  if (tid == 0) flagS = 0;
  int localf = 0;
  if (br == 0) {
    for (int i = tid; i < NA*HD; i += 512) hwl[i] = ahw[i];
    if (tid < NA) hbl[tid] = ahb[tid];
    if (tid < HD) { pa[tid] = alnw[tid]; pb[tid] = alnb[tid]; }
    for (int i = 2*tid + 1; i < 4096; i += 1024) localf |= action[i];
  } else {
    if (tid < HD) { pa[tid] = clnw[tid]; pb[tid] = clnb[tid]; pc[tid] = chw[tid]; }
    if (tid == 0) hbl[0] = chb[0];
  }
  __syncthreads();   // params + flagS=0 visible; hs stores drained
  if (localf) flagS = 1;
  __syncthreads();

  if (br == 0) {
    int fl = flagS;
    for (int kk = 0; kk < 2; ++kk) {
      int k = tid + kk*512;
      int rr = (k >> 3)*BB + base8 + (k & 7);
      int act = fl ? action[rr] : (int)(((const long long*)action)[rr]);
      dout[rr] = (float)act;
      if (act < 0) act = 0;
      if (act > NA-1) act = NA-1;
      uint32_t hw_[64];
      const uint32_t* hp2 = (const uint32_t*)(feat + (size_t)rr*HD);
      for (int i = 0; i < 16; ++i) *(uint4*)&hw_[i*4] = ((const uint4*)hp2)[i];
      float s = 0.0f, ss = 0.0f;
      for (int i = 0; i < 64; ++i) {
        float f0 = bf2f(hw_[i] & 0xffffu), f1 = bf2f(hw_[i] >> 16);
        s += f0 + f1; ss += f0*f0 + f1*f1;
      }
      float mu = s * (1.0f/128.0f);
      float var = ss * (1.0f/128.0f) - mu*mu;
      float rstd = rsqrtf(var + 1e-5f);
      float lg[NA];
      for (int a = 0; a < NA; ++a) lg[a] = hbl[a];
      for (int i = 0; i < 64; ++i) {
        int k0 = i*2;
        float f0 = (bf2f(hw_[i] & 0xffffu) - mu)*rstd*pa[k0]   + pb[k0];
        float f1 = (bf2f(hw_[i] >> 16)     - mu)*rstd*pa[k0+1] + pb[k0+1];
        for (int a = 0; a < NA; ++a)
          lg[a] += f0*hwl[a*HD + k0] + f1*hwl[a*HD + k0 + 1];
      }
      float mx = lg[0];
      for (int a = 1; a < NA; ++a) mx = fmaxf(mx, lg[a]);
      float se = 0.0f;
      for (int a = 0; a < NA; ++a) se += __expf(lg[a] - mx);
      float lse = __logf(se);
      dout[(size_t)NN + rr] = lg[act] - mx - lse;
      float ent = 0.0f;
      for (int a = 0; a < NA; ++a) { float lp = lg[a] - mx - lse; ent -= __expf(lp)*lp; }
      dout[(size_t)2*NN + rr] = ent;
    }
  } else {
    for (int kk = 0; kk < 2; ++kk) {
      int k = tid + kk*512;
      int rr = (k >> 3)*BB + base8 + (k & 7);
      uint32_t hw_[64];
      const uint32_t* hp2 = (const uint32_t*)(feat + (size_t)rr*HD);
      for (int i = 0; i < 16; ++i) *(uint4*)&hw_[i*4] = ((const uint4*)hp2)[i];
      float s = 0.0f, ss = 0.0f;
      for (int i = 0; i < 64; ++i) {
        float f0 = bf2f(hw_[i] & 0xffffu), f1 = bf2f(hw_[i] >> 16);
        s += f0 + f1; ss += f0*f0 + f1*f1;
      }
      float mu = s * (1.0f/128.0f);
      float var = ss * (1.0f/128.0f) - mu*mu;
      float rstd = rsqrtf(var + 1e-5f);
      float v = hbl[0];
      for (int i = 0; i < 64; ++i) {
        int k0 = i*2;
        float f0 = (bf2f(hw_[i] & 0xffffu) - mu)*rstd*pa[k0]   + pb[k0];
        float f1 = (bf2f(hw_[i] >> 16)     - mu)*rstd*pa[k0+1] + pb[k0+1];
        v += f0*pc[k0] + f1*pc[k0+1];
      }
      dout[(size_t)3*NN + rr] = v;
    }
  }
}

extern "C" void kernel_launch(void* const* d_in, const int* in_sizes, int n_in,
                              void* d_out, int out_size, void* d_ws, size_t ws_size,
                              hipStream_t stream) {
  (void)in_sizes; (void)n_in; (void)out_size; (void)ws_size;
  const float* x    = (const float*)d_in[0];
  const float* ah0  = (const float*)d_in[1];
  const float* ac0  = (const float*)d_in[2];
  const float* ch0  = (const float*)d_in[3];
  const float* cc0  = (const float*)d_in[4];
  const int*   done = (const int*)d_in[5];
  const int*   act  = (const int*)d_in[6];
  const float* aw1  = (const float*)d_in[7];
  const float* ab1  = (const float*)d_in[8];
  const float* aw2  = (const float*)d_in[9];
  const float* ab2  = (const float*)d_in[10];
  const float* aflnw= (const float*)d_in[11];
  const float* aflnb= (const float*)d_in[12];
  const float* awih = (const float*)d_in[13];
  const float* awhh = (const float*)d_in[14];
  const float* a_b  = (const float*)d_in[15];
  const float* alnw = (const float*)d_in[16];
  const float* alnb = (const float*)d_in[17];
  const float* ahw  = (const float*)d_in[18];
  const float* ahb  = (const float*)d_in[19];
  const float* cw1  = (const float*)d_in[20];
  const float* cb1  = (const float*)d_in[21];
  const float* cw2  = (const float*)d_in[22];
  const float* cb2  = (const float*)d_in[23];
  const float* cflnw= (const float*)d_in[24];
  const float* cflnb= (const float*)d_in[25];
  const float* cwih = (const float*)d_in[26];
  const float* cwhh = (const float*)d_in[27];
  const float* c_b  = (const float*)d_in[28];
  const float* clnw = (const float*)d_in[29];
  const float* clnb = (const float*)d_in[30];
  const float* chw  = (const float*)d_in[31];
  const float* chb  = (const float*)d_in[32];

  unsigned short* featb = (unsigned short*)d_ws;   // [2][NN*HD] bf16
  float* out = (float*)d_out;

  fused_kernel<<<256, 512, 0, stream>>>(
      x, done, act,
      aw1, ab1, aw2, ab2, aflnw, aflnb, awih, awhh, a_b, alnw, alnb, ahw, ahb,
      cw1, cb1, cw2, cb2, cflnw, cflnb, cwih, cwhh, c_b, clnw, clnb, chw, chb,
      ah0, ac0, ch0, cc0,
      featb, out);
}

// Round 9
// 413.581 us; speedup vs baseline: 1.3113x; 1.0793x over previous
//
#include <hip/hip_runtime.h>
#include <stdint.h>
#include <stddef.h>

#define OBS 128
#define F1D 256
#define HD  128
#define NA  18
#define TT  128
#define BB  1024
#define NN  (TT*BB)
#define LOG2E 1.442695041f

typedef __attribute__((ext_vector_type(8))) short short8;
typedef __attribute__((ext_vector_type(4))) float f32x4;

__device__ __forceinline__ unsigned short f2bf(float f) {
  union { float f; uint32_t u; } v; v.f = f;
  uint32_t u = v.u;
  u += 0x7fffu + ((u >> 16) & 1u);   // RNE
  return (unsigned short)(u >> 16);
}
__device__ __forceinline__ float bf2f(uint32_t hu) {
  union { uint32_t u; float f; } v; v.u = hu << 16;
  return v.f;
}
__device__ __forceinline__ f32x4 mfma16(short8 a, short8 b, f32x4 c) {
  return __builtin_amdgcn_mfma_f32_16x16x32_bf16(a, b, c, 0, 0, 0);
}
// f32 -> bf16 fragment (8 consecutive, scaled)
__device__ __forceinline__ short8 cvt8(const float* p, float sc) {
  float4 a = *(const float4*)p;
  float4 b = *(const float4*)(p + 4);
  union { unsigned short u[8]; short8 s; } o;
  o.u[0]=f2bf(a.x*sc); o.u[1]=f2bf(a.y*sc); o.u[2]=f2bf(a.z*sc); o.u[3]=f2bf(a.w*sc);
  o.u[4]=f2bf(b.x*sc); o.u[5]=f2bf(b.y*sc); o.u[6]=f2bf(b.z*sc); o.u[7]=f2bf(b.w*sc);
  return o.s;
}
// pin: empty volatile asm with tied SCALAR "+v" operands (R6/R7 lessons).
__device__ __forceinline__ short8 pin(short8 v) {
  int4 i = *(int4*)&v;
  asm volatile("" : "+v"(i.x), "+v"(i.y), "+v"(i.z), "+v"(i.w));
  return *(short8*)&i;
}

// One WG = (branch, 8-batch-row slice). Fully self-contained.
// Phase A: feature MLP; Phase B: masked LSTM (M=8 stride-2); Phase C: heads
// (R9: Phase C rewritten — actor logits via MFMA GEMM, LN in registers,
//  predicated logp[act]; kills the hw_[64]/lg[act] scratch spill that cost
//  ~130 MB of scratch write traffic and ~170 us in R1-R8).
__global__ __launch_bounds__(512, 2) void fused_kernel(
    const float* __restrict__ x, const int* __restrict__ done,
    const int* __restrict__ action,
    const float* __restrict__ aw1, const float* __restrict__ ab1,
    const float* __restrict__ aw2, const float* __restrict__ ab2,
    const float* __restrict__ aflnw, const float* __restrict__ aflnb,
    const float* __restrict__ awih, const float* __restrict__ awhh,
    const float* __restrict__ a_b,
    const float* __restrict__ alnw, const float* __restrict__ alnb,
    const float* __restrict__ ahw, const float* __restrict__ ahb,
    const float* __restrict__ cw1, const float* __restrict__ cb1,
    const float* __restrict__ cw2, const float* __restrict__ cb2,
    const float* __restrict__ cflnw, const float* __restrict__ cflnb,
    const float* __restrict__ cwih, const float* __restrict__ cwhh,
    const float* __restrict__ c_b,
    const float* __restrict__ clnw, const float* __restrict__ clnb,
    const float* __restrict__ chw, const float* __restrict__ chb,
    const float* __restrict__ ah0, const float* __restrict__ ac0,
    const float* __restrict__ ch0, const float* __restrict__ cc0,
    unsigned short* __restrict__ featg, float* __restrict__ dout)
{
  int g = blockIdx.x;
  int br = g >> 7;
  int chunk = g & 127;
  int base8 = chunk * 8;

  const float* w1  = br ? cw1 : aw1;     // [256][128]
  const float* b1  = br ? cb1 : ab1;
  const float* w2  = br ? cw2 : aw2;     // [128][256]
  const float* b2  = br ? cb2 : ab2;
  const float* flw = br ? cflnw : aflnw;
  const float* flb = br ? cflnb : aflnb;
  const float* wih = br ? cwih : awih;   // [512][128]
  const float* whh = br ? cwhh : awhh;
  const float* gb  = br ? c_b : a_b;
  const float* h0  = br ? ch0 : ah0;
  const float* c0  = br ? cc0 : ac0;
  unsigned short* feat = featg + (size_t)br * NN * HD;

  // Phase A: xs(16K)+h1s(32K)+lnsum(2K)=50K  |  Phase C: hsn(32K)+cout(18K)
  __shared__ __align__(16) char smemA[51200];
  __shared__ float mls[(TT+1)*8];              // 1 - done, padded t=TT
  __shared__ unsigned short hlds[2][8*128];    // double-buffered masked h
  __shared__ float pa[HD], pb[HD], cws[HD];
  __shared__ float hbl[NA];
  __shared__ float cbsS;
  __shared__ int flagS;

  int tid = threadIdx.x;
  int w = tid >> 6, lane = tid & 63, q = lane >> 4, ln = lane & 15;
  int team = tid >> 8, t_tid = tid & 255, w4 = w & 3;

  // ================= Phase A: feature MLP =================
  {
    unsigned short* xst  = (unsigned short*)smemA + team*4096;           // 32*128
    unsigned short* h1st = (unsigned short*)(smemA + 16384) + team*8192; // 32*256
    float*          lnst = (float*)(smemA + 49152) + team*256;           // 32*8

    short8 b1f[4][4]; float b1v[4];
    #pragma unroll
    for (int ct = 0; ct < 4; ++ct) {
      int nn = w4*64 + ct*16 + ln;
      b1v[ct] = b1[nn];
      #pragma unroll
      for (int kf = 0; kf < 4; ++kf)
        b1f[ct][kf] = pin(cvt8(&w1[nn*OBS + kf*32 + q*8], 1.0f));
    }
    short8 b2f[2][8]; float b2v[2], lwv[2], lbv[2];
    #pragma unroll
    for (int nt = 0; nt < 2; ++nt) {
      int nn = w4*32 + nt*16 + ln;
      b2v[nt] = b2[nn]; lwv[nt] = flw[nn]; lbv[nt] = flb[nn];
      #pragma unroll
      for (int kf = 0; kf < 8; ++kf)
        b2f[nt][kf] = pin(cvt8(&w2[nn*F1D + kf*32 + q*8], 1.0f));
    }
    // tile = 4 timesteps x 8 batch rows = 32 rows; team handles tiles 2j+team
    float4 xr[4];
    #pragma unroll
    for (int s = 0; s < 4; ++s) {
      int e4 = t_tid + s*256;
      int r = e4 >> 5, c4 = e4 & 31;
      size_t grow = (size_t)(team*4 + (r>>3))*BB + base8 + (r&7);
      xr[s] = ((const float4*)x)[grow*32 + c4];
    }
    for (int j = 0; j < 16; ++j) {
      int jj = j*2 + team;
      #pragma unroll
      for (int s = 0; s < 4; ++s) {
        int e = (t_tid + s*256) * 4;
        int r = e >> 7, k = e & 127;
        int ad = r*128 + ((((k>>3) ^ (r&15)) << 3)) + (k&7);
        uint2 d;
        d.x = (uint32_t)f2bf(xr[s].x) | ((uint32_t)f2bf(xr[s].y) << 16);
        d.y = (uint32_t)f2bf(xr[s].z) | ((uint32_t)f2bf(xr[s].w) << 16);
        *(uint2*)&xst[ad] = d;
      }
      __syncthreads();                 // B1: xs ready
      {
        int jjn = (j < 15) ? jj + 2 : jj;
        #pragma unroll
        for (int s = 0; s < 4; ++s) {
          int e4 = t_tid + s*256;
          int r = e4 >> 5, c4 = e4 & 31;
          size_t grow = (size_t)(jjn*4 + (r>>3))*BB + base8 + (r&7);
          xr[s] = ((const float4*)x)[grow*32 + c4];
        }
      }
      // ---- G1 ----
      short8 af[2][4];
      #pragma unroll
      for (int mt = 0; mt < 2; ++mt)
        #pragma unroll
        for (int kf = 0; kf < 4; ++kf)
          af[mt][kf] = *(const short8*)&xst[(mt*16 + ln)*128 + ((((kf<<2)|q) ^ ln) << 3)];
      #pragma unroll
      for (int ct = 0; ct < 4; ++ct) {
        int nn = w4*64 + ct*16 + ln;
        #pragma unroll
        for (int mt = 0; mt < 2; ++mt) {
          f32x4 acc = {b1v[ct], b1v[ct], b1v[ct], b1v[ct]};
          #pragma unroll
          for (int kf = 0; kf < 4; ++kf) acc = mfma16(af[mt][kf], b1f[ct][kf], acc);
          #pragma unroll
          for (int rg = 0; rg < 4; ++rg) {
            float v = acc[rg] > 0.0f ? acc[rg] : 0.0f;
            int rrow = mt*16 + q*4 + rg;
            h1st[rrow*256 + (((nn>>3) ^ (rrow&15)) << 3) + (nn&7)] = f2bf(v);
          }
        }
      }
      __syncthreads();                 // B2: h1s ready
      // ---- G2 ----
      f32x4 acc2[2][2];
      #pragma unroll
      for (int mt = 0; mt < 2; ++mt) {
        short8 ah[8];
        #pragma unroll
        for (int kf = 0; kf < 8; ++kf)
          ah[kf] = *(const short8*)&h1st[(mt*16 + ln)*256 + ((((kf<<2)|q) ^ ln) << 3)];
        #pragma unroll
        for (int nt = 0; nt < 2; ++nt) {
          f32x4 acc = {b2v[nt], b2v[nt], b2v[nt], b2v[nt]};
          #pragma unroll
          for (int kf = 0; kf < 8; ++kf) acc = mfma16(ah[kf], b2f[nt][kf], acc);
          acc2[nt][mt] = acc;
        }
      }
      // ---- LN partials ----
      #pragma unroll
      for (int mt = 0; mt < 2; ++mt)
        #pragma unroll
        for (int rg = 0; rg < 4; ++rg) {
          float s = acc2[0][mt][rg] + acc2[1][mt][rg];
          float ssq = acc2[0][mt][rg]*acc2[0][mt][rg] + acc2[1][mt][rg]*acc2[1][mt][rg];
          #pragma unroll
          for (int m = 1; m < 16; m <<= 1) { s += __shfl_xor(s, m); ssq += __shfl_xor(ssq, m); }
          if (ln == 0) {
            int r = mt*16 + q*4 + rg;
            lnst[r*8 + w4*2]     = s;
            lnst[r*8 + w4*2 + 1] = ssq;
          }
        }
      __syncthreads();                 // B3: lnsum ready
      #pragma unroll
      for (int mt = 0; mt < 2; ++mt)
        #pragma unroll
        for (int rg = 0; rg < 4; ++rg) {
          int r = mt*16 + q*4 + rg;
          float4 p0 = *(const float4*)&lnst[r*8];
          float4 p1 = *(const float4*)&lnst[r*8 + 4];
          float S  = p0.x + p0.z + p1.x + p1.z;
          float SS = p0.y + p0.w + p1.y + p1.w;
          float mu = S * (1.0f/128.0f);
          float var = SS * (1.0f/128.0f) - mu*mu;
          float rstd = rsqrtf(var + 1e-5f);
          size_t grow = (size_t)(jj*4 + (r>>3))*BB + base8 + (r&7);
          #pragma unroll
          for (int nt = 0; nt < 2; ++nt) {
            float t = (acc2[nt][mt][rg] - mu) * rstd * lwv[nt] + lbv[nt];
            if (t < 0.0f) t = 0.0f;
            feat[grow*HD + w4*32 + nt*16 + ln] = f2bf(t);
          }
        }
      __syncthreads();                 // Bend
    }
  }

  // ================= Phase B: masked LSTM (M=8, stride-2 packing) =================
  int n = w*16 + ln;
  {
    short8 bfr[4][8]; float bias[4];
    #pragma unroll
    for (int g4 = 0; g4 < 4; ++g4) {
      int gn = g4*128 + n;
      float sc = (g4 == 2) ? -2.0f*LOG2E : -LOG2E;   // gate order i,f,g,o
      bias[g4] = gb[gn] * sc;
      #pragma unroll
      for (int kf = 0; kf < 8; ++kf) {
        const float* src = (kf < 4) ? &wih[gn*HD + kf*32 + q*8]
                                    : &whh[gn*HD + (kf-4)*32 + q*8];
        bfr[g4][kf] = pin(cvt8(src, sc));
      }
    }
    for (int i = tid; i < (TT+1)*8; i += 512)
      mls[i] = (i < TT*8) ? 1.0f - (float)done[(i>>3)*BB + base8 + (i&7)] : 1.0f;

    const int loff = (base8 + (ln>>1))*HD + q*8;   // A-row ln -> batch row ln>>1
    int soff[2], hoffw[2], haddr[4];
    #pragma unroll
    for (int j = 0; j < 2; ++j) {
      int r = q*2 + j;
      soff[j]  = (base8 + r)*HD + n;
      hoffw[j] = r*128 + (((n>>3) ^ r) << 3) + (n&7);
    }
    #pragma unroll
    for (int kf = 0; kf < 4; ++kf) {
      int rr = ln >> 1;
      haddr[kf] = rr*128 + ((((kf<<2)|q) ^ rr) << 3);
    }
    float hp[2], cp[2]; unsigned short hu_prev[2];
    #pragma unroll
    for (int j = 0; j < 2; ++j) {
      int b = base8 + q*2 + j;
      hp[j] = h0[b*HD + n];
      cp[j] = c0[b*HD + n];
      hu_prev[j] = 0;
    }
    short8 afr[4], nfr[4];
    #pragma unroll
    for (int kf = 0; kf < 4; ++kf)
      afr[kf] = *(const short8*)&feat[loff + kf*32];    // feat[0]
    __syncthreads();   // mls ready
    #pragma unroll
    for (int j = 0; j < 2; ++j) {
      float m = mls[q*2 + j];
      cp[j] *= m;
      hlds[0][hoffw[j]] = f2bf(hp[j] * m);
    }
    __syncthreads();   // hlds[0] ready

#define LSTM_STEP(TTT, CUR, NXT, HB)                                           \
  {                                                                            \
    short8 hfr[4];                                                             \
    _Pragma("unroll")                                                          \
    for (int kf = 0; kf < 4; ++kf)                                             \
      hfr[kf] = *(const short8*)&hlds[HB][haddr[kf]];                          \
    {                                                                          \
      int tp = (TTT) > 0 ? (TTT) - 1 : 0;                                      \
      unsigned short* sq = feat + (size_t)tp * (BB*HD);                        \
      sq[soff[0]] = hu_prev[0];                                                \
      sq[soff[1]] = hu_prev[1];                                                \
    }                                                                          \
    int tn = ((TTT) + 1 < TT) ? (TTT) + 1 : TT - 1;                            \
    const unsigned short* fq = feat + (size_t)tn * (BB*HD);                    \
    _Pragma("unroll")                                                          \
    for (int kf = 0; kf < 4; ++kf)                                             \
      NXT[kf] = *(const short8*)&fq[loff + kf*32];                             \
    f32x4 a0 = {bias[0],bias[0],bias[0],bias[0]};                              \
    f32x4 a1 = {bias[1],bias[1],bias[1],bias[1]};                              \
    f32x4 a2 = {bias[2],bias[2],bias[2],bias[2]};                              \
    f32x4 a3 = {bias[3],bias[3],bias[3],bias[3]};                              \
    _Pragma("unroll")                                                          \
    for (int kf = 0; kf < 4; ++kf) {                                           \
      a0 = mfma16(CUR[kf], bfr[0][kf], a0);                                    \
      a1 = mfma16(CUR[kf], bfr[1][kf], a1);                                    \
      a2 = mfma16(CUR[kf], bfr[2][kf], a2);                                    \
      a3 = mfma16(CUR[kf], bfr[3][kf], a3);                                    \
    }                                                                          \
    _Pragma("unroll")                                                          \
    for (int kf = 0; kf < 4; ++kf) {                                           \
      a0 = mfma16(hfr[kf], bfr[0][4+kf], a0);                                  \
      a1 = mfma16(hfr[kf], bfr[1][4+kf], a1);                                  \
      a2 = mfma16(hfr[kf], bfr[2][4+kf], a2);                                  \
      a3 = mfma16(hfr[kf], bfr[3][4+kf], a3);                                  \
    }                                                                          \
    float2 mn = *(const float2*)&mls[((TTT)+1)*8 + q*2];                       \
    _Pragma("unroll")                                                          \
    for (int j = 0; j < 2; ++j) {                                              \
      int rg = j*2;  /* C rows duplicated pairwise; even reg = valid copy */   \
      float si = __builtin_amdgcn_rcpf(1.0f + __builtin_amdgcn_exp2f(a0[rg])); \
      float sf = __builtin_amdgcn_rcpf(1.0f + __builtin_amdgcn_exp2f(a1[rg])); \
      float tg = __builtin_fmaf(2.0f,                                          \
                   __builtin_amdgcn_rcpf(1.0f + __builtin_amdgcn_exp2f(a2[rg])), -1.0f); \
      float so = __builtin_amdgcn_rcpf(1.0f + __builtin_amdgcn_exp2f(a3[rg])); \
      float cn = __builtin_fmaf(sf, cp[j], si*tg);                             \
      float th = __builtin_fmaf(2.0f,                                          \
                   __builtin_amdgcn_rcpf(1.0f + __builtin_amdgcn_exp2f(-2.0f*LOG2E*cn)), -1.0f); \
      float hn = so * th;                                                      \
      unsigned short hu = f2bf(hn);                                            \
      hu_prev[j] = hu;                                                         \
      bool live = ((&mn.x)[j] != 0.0f);                                        \
      cp[j] = live ? cn : 0.0f;                                                \
      hp[j] = hn;                                                              \
      hlds[(HB)^1][hoffw[j]] = live ? hu : (unsigned short)0;                  \
    }                                                                          \
    __syncthreads();                                                           \
  }

    for (int t = 0; t < TT; t += 2) {
      LSTM_STEP(t,   afr, nfr, 0)
      LSTM_STEP(t+1, nfr, afr, 1)
    }
#undef LSTM_STEP

    {
      unsigned short* sq = feat + (size_t)(TT-1)*(BB*HD);
      sq[soff[0]] = hu_prev[0];
      sq[soff[1]] = hu_prev[1];
    }
    {
      float* outh = dout + (size_t)(4 + br*2) * NN;
      float* outc = dout + (size_t)(5 + br*2) * NN;
      #pragma unroll
      for (int j = 0; j < 2; ++j) {
        int b = base8 + q*2 + j;
        outh[b*HD + n] = hp[j];
        outc[b*HD + n] = cp[j];
      }
    }
  }

  // ================= Phase C: heads (GEMM actor / inline critic) =================
  if (tid == 0) flagS = 0;
  if (tid < HD) {
    pa[tid] = br ? clnw[tid] : alnw[tid];
    pb[tid] = br ? clnb[tid] : alnb[tid];
    if (br) cws[tid] = chw[tid];
  }
  int localf = 0;
  if (br == 0) {
    if (tid < NA) hbl[tid] = ahb[tid];
    for (int i = 2*tid + 1; i < 4096; i += 1024) localf |= action[i];
  } else if (tid == 0) cbsS = chb[0];
  __syncthreads();   // params + flagS=0 visible; hs stores drained
  if (localf) flagS = 1;
  __syncthreads();

  int sub = tid & 3, kidx = tid >> 2;
  if (br == 0) {
    unsigned short* hsn = (unsigned short*)smemA;   // [128][128] bf16 swizzled
    float* co = (float*)(smemA + 32768);            // [128][36] f32
    // head B-frags: actions 0..17, zero-padded to 32 rows; pinned
    short8 hbf[2][4];
    #pragma unroll
    for (int nt = 0; nt < 2; ++nt) {
      int nn = nt*16 + ln;
      #pragma unroll
      for (int kf = 0; kf < 4; ++kf) {
        short8 z = {0,0,0,0,0,0,0,0};
        hbf[nt][kf] = (nn < NA) ? pin(cvt8(&ahw[nn*HD + kf*32 + q*8], 1.0f)) : z;
      }
    }
    int fl = flagS;
    for (int ch = 0; ch < 8; ++ch) {
      // --- stage A: LN (4 lanes/row) -> hsn bf16 swizzled ---
      {
        int k = ch*128 + kidx;
        int rrow = (k >> 3)*BB + base8 + (k & 7);
        const unsigned short* hp2 = feat + (size_t)rrow*HD + sub*32;
        uint4 d0 = *(const uint4*)hp2;
        uint4 d1 = *(const uint4*)(hp2 + 8);
        uint4 d2 = *(const uint4*)(hp2 + 16);
        uint4 d3 = *(const uint4*)(hp2 + 24);
        float nv[32];
        #define UP(W_, B_) { nv[B_] = bf2f((W_) & 0xffffu); nv[(B_)+1] = bf2f((W_) >> 16); }
        UP(d0.x,0) UP(d0.y,2) UP(d0.z,4) UP(d0.w,6)
        UP(d1.x,8) UP(d1.y,10) UP(d1.z,12) UP(d1.w,14)
        UP(d2.x,16) UP(d2.y,18) UP(d2.z,20) UP(d2.w,22)
        UP(d3.x,24) UP(d3.y,26) UP(d3.z,28) UP(d3.w,30)
        #undef UP
        float s = 0.0f, ssq = 0.0f;
        #pragma unroll
        for (int j = 0; j < 32; ++j) { s += nv[j]; ssq += nv[j]*nv[j]; }
        s += __shfl_xor(s, 1); ssq += __shfl_xor(ssq, 1);
        s += __shfl_xor(s, 2); ssq += __shfl_xor(ssq, 2);
        float mu = s * (1.0f/128.0f);
        float var = ssq * (1.0f/128.0f) - mu*mu;
        float rstd = rsqrtf(var + 1e-5f);
        #pragma unroll
        for (int cc = 0; cc < 4; ++cc) {
          unsigned short ob[8];
          #pragma unroll
          for (int j = 0; j < 8; ++j) {
            int c = sub*32 + cc*8 + j;
            ob[j] = f2bf((nv[cc*8+j] - mu) * rstd * pa[c] + pb[c]);
          }
          int c8 = sub*4 + cc;
          *(short8*)&hsn[kidx*128 + ((c8 ^ (kidx & 15)) << 3)] = *(short8*)ob;
        }
      }
      __syncthreads();
      // --- stage B: logits GEMM (wave w -> rows w*16..+16) ---
      {
        short8 afh[4];
        #pragma unroll
        for (int kf = 0; kf < 4; ++kf)
          afh[kf] = *(const short8*)&hsn[(w*16 + ln)*128 + ((((kf<<2)|q) ^ ln) << 3)];
        #pragma unroll
        for (int nt = 0; nt < 2; ++nt) {
          f32x4 acc = {0.0f, 0.0f, 0.0f, 0.0f};
          #pragma unroll
          for (int kf = 0; kf < 4; ++kf) acc = mfma16(afh[kf], hbf[nt][kf], acc);
          #pragma unroll
          for (int rg = 0; rg < 4; ++rg)
            co[(w*16 + q*4 + rg)*36 + nt*16 + ln] = acc[rg];
        }
      }
      __syncthreads();
      // --- stage C: softmax/logp/entropy (1 thread/row, tid<128) ---
      if (tid < 128) {
        int k = ch*128 + tid;
        int rrow = (k >> 3)*BB + base8 + (k & 7);
        int act = fl ? action[rrow] : (int)(((const long long*)action)[rrow]);
        dout[rrow] = (float)act;
        int aidx = act < 0 ? 0 : (act > NA-1 ? NA-1 : act);
        float lg[NA];
        #pragma unroll
        for (int a = 0; a < NA; ++a) lg[a] = co[tid*36 + a] + hbl[a];
        float mx = lg[0];
        #pragma unroll
        for (int a = 1; a < NA; ++a) mx = fmaxf(mx, lg[a]);
        float se = 0.0f;
        #pragma unroll
        for (int a = 0; a < NA; ++a) se += __expf(lg[a] - mx);
        float lse = __logf(se);
        float lpa = 0.0f, ent = 0.0f;
        #pragma unroll
        for (int a = 0; a < NA; ++a) {
          float lp = lg[a] - mx - lse;
          ent -= __expf(lp) * lp;
          lpa += (a == aidx) ? lp : 0.0f;
        }
        dout[(size_t)NN + rrow] = lpa;
        dout[(size_t)2*NN + rrow] = ent;
      }
      __syncthreads();
    }
  } else {
    // critic: inline LN + dot, no GEMM, no barriers needed
    for (int ch = 0; ch < 8; ++ch) {
      int k = ch*128 + kidx;
      int rrow = (k >> 3)*BB + base8 + (k & 7);
      const unsigned short* hp2 = feat + (size_t)rrow*HD + sub*32;
      uint4 d0 = *(const uint4*)hp2;
      uint4 d1 = *(const uint4*)(hp2 + 8);
      uint4 d2 = *(const uint4*)(hp2 + 16);
      uint4 d3 = *(const uint4*)(hp2 + 24);
      float nv[32];
      #define UP(W_, B_) { nv[B_] = bf2f((W_) & 0xffffu); nv[(B_)+1] = bf2f((W_) >> 16); }
      UP(d0.x,0) UP(d0.y,2) UP(d0.z,4) UP(d0.w,6)
      UP(d1.x,8) UP(d1.y,10) UP(d1.z,12) UP(d1.w,14)
      UP(d2.x,16) UP(d2.y,18) UP(d2.z,20) UP(d2.w,22)
      UP(d3.x,24) UP(d3.y,26) UP(d3.z,28) UP(d3.w,30)
      #undef UP
      float s = 0.0f, ssq = 0.0f;
      #pragma unroll
      for (int j = 0; j < 32; ++j) { s += nv[j]; ssq += nv[j]*nv[j]; }
      s += __shfl_xor(s, 1); ssq += __shfl_xor(ssq, 1);
      s += __shfl_xor(s, 2); ssq += __shfl_xor(ssq, 2);
      float mu = s * (1.0f/128.0f);
      float var = ssq * (1.0f/128.0f) - mu*mu;
      float rstd = rsqrtf(var + 1e-5f);
      float dot = 0.0f;
      #pragma unroll
      for (int j = 0; j < 32; ++j) {
        int c = sub*32 + j;
        dot += ((nv[j] - mu) * rstd * pa[c] + pb[c]) * cws[c];
      }
      dot += __shfl_xor(dot, 1);
      dot += __shfl_xor(dot, 2);
      if (sub == 0) dout[(size_t)3*NN + rrow] = dot + cbsS;
    }
  }
}

extern "C" void kernel_launch(void* const* d_in, const int* in_sizes, int n_in,
                              void* d_out, int out_size, void* d_ws, size_t ws_size,
                              hipStream_t stream) {
  (void)in_sizes; (void)n_in; (void)out_size; (void)ws_size;
  const float* x    = (const float*)d_in[0];
  const float* ah0  = (const float*)d_in[1];
  const float* ac0  = (const float*)d_in[2];
  const float* ch0  = (const float*)d_in[3];
  const float* cc0  = (const float*)d_in[4];
  const int*   done = (const int*)d_in[5];
  const int*   act  = (const int*)d_in[6];
  const float* aw1  = (const float*)d_in[7];
  const float* ab1  = (const float*)d_in[8];
  const float* aw2  = (const float*)d_in[9];
  const float* ab2  = (const float*)d_in[10];
  const float* aflnw= (const float*)d_in[11];
  const float* aflnb= (const float*)d_in[12];
  const float* awih = (const float*)d_in[13];
  const float* awhh = (const float*)d_in[14];
  const float* a_b  = (const float*)d_in[15];
  const float* alnw = (const float*)d_in[16];
  const float* alnb = (const float*)d_in[17];
  const float* ahw  = (const float*)d_in[18];
  const float* ahb  = (const float*)d_in[19];
  const float* cw1  = (const float*)d_in[20];
  const float* cb1  = (const float*)d_in[21];
  const float* cw2  = (const float*)d_in[22];
  const float* cb2  = (const float*)d_in[23];
  const float* cflnw= (const float*)d_in[24];
  const float* cflnb= (const float*)d_in[25];
  const float* cwih = (const float*)d_in[26];
  const float* cwhh = (const float*)d_in[27];
  const float* c_b  = (const float*)d_in[28];
  const float* clnw = (const float*)d_in[29];
  const float* clnb = (const float*)d_in[30];
  const float* chw  = (const float*)d_in[31];
  const float* chb  = (const float*)d_in[32];

  unsigned short* featb = (unsigned short*)d_ws;   // [2][NN*HD] bf16
  float* out = (float*)d_out;

  fused_kernel<<<256, 512, 0, stream>>>(
      x, done, act,
      aw1, ab1, aw2, ab2, aflnw, aflnb, awih, awhh, a_b, alnw, alnb, ahw, ahb,
      cw1, cb1, cw2, cb2, cflnw, cflnb, cwih, cwhh, c_b, clnw, clnb, chw, chb,
      ah0, ac0, ch0, cc0,
      featb, out);
}